// Round 9
// baseline (192.825 us; speedup 1.0000x reference)
//
#include <hip/hip_runtime.h>

// ---------------------------------------------------------------------------
// MultiHeadAttention: B=2, T=2048, C=1024, H=16, D=64
// prep (cast x -> bf16 ; transpose W_qkv, W_out -> bf16 [N][K], fused) ;
// QKV GEMM -> Q (prescaled 0.125*log2e), K [b,h,t,d], V^T [b,h,d,t] ;
// flash attention (fixed-base softmax), Q in regs, K/V glds dbuf
// XOR-swizzled LDS, precomputed bases, kt unrolled x2.
// R6: PV + row-sum packed into mfma_f32_16x16x32 (K=32), 36 MFMA/tile.
// R7: XCD-chunked swizzle (FETCH 73.8 -> 20.6 MB measured).
// R9: Vtb t-axis pre-permuted => PV A-operand is one ds_read_b128; bank
// conflicts 4.19M -> 0 (measured).
// R10: split-K fused into one 512-thread block, in-kernel LDS combine.
// R11: out GEMM 64x128 (2 blocks/CU); qkv V^T ushort4 stores; prep fused.
// R12: attn VALU diet: raw v_exp_f32 (OCML exp2f was ~8 instrs), pinned
// zero4 C-init, v_rcp epilogue. attn 55.7 -> <44 us (measured).
// R13: qkv GEMM retiled 128x128 -> 64x128: grid 768 -> 1536 = 6 blocks/CU
// (was 3 = 3 waves/SIMD -> latency-bound: MfmaUtil 22%, VALUBusy 38%,
// Occ 23%). LDS 24KB, acc[2][4]/wave. Bank-conflict swizzle evaluated and
// rejected: 64B-row b128 reads are LDS-BW-serialized inherently; XOR-4
// provably doesn't change bank-start distribution.
// ---------------------------------------------------------------------------

typedef float  f32x4  __attribute__((ext_vector_type(4)));
typedef __bf16 bf16x8 __attribute__((ext_vector_type(8)));

#define QSCALE 0.18033688011112042f   // 0.125 * log2(e)

#if __has_builtin(__builtin_amdgcn_exp2f)
#define EXP2(x) __builtin_amdgcn_exp2f(x)
#else
#define EXP2(x) exp2f(x)
#endif
#if __has_builtin(__builtin_amdgcn_rcpf)
#define RCP(x) __builtin_amdgcn_rcpf(x)
#else
#define RCP(x) (1.0f / (x))
#endif

static __device__ __forceinline__ f32x4 mfma32(bf16x8 a, bf16x8 b, f32x4 c) {
    return __builtin_amdgcn_mfma_f32_16x16x32_bf16(a, b, c, 0, 0, 0);
}

static __device__ __forceinline__ bf16x8 ld8(const unsigned short* p) {
    return __builtin_bit_cast(bf16x8, *(const uint4*)p);
}
static __device__ __forceinline__ unsigned short bfbits(float f) {
    __bf16 h = (__bf16)f;
    return __builtin_bit_cast(unsigned short, h);
}

static __device__ __forceinline__ void glds16(const unsigned short* g,
                                              unsigned short* lds_base) {
    __builtin_amdgcn_global_load_lds(
        (const __attribute__((address_space(1))) unsigned int*)g,
        (__attribute__((address_space(3))) unsigned int*)lds_base, 16, 0, 0);
}

// ------------------------------------------------------------ prep (fused)
// blocks [0,4096): cast x -> bf16 (float4/ushort4)
// blocks [4096,7168): transpose+cast W_qkv (96x32 tiles of 32x32)
// blocks [7168,8192): transpose+cast W_out (32x32 tiles)
__global__ __launch_bounds__(256) void prep_kernel(
    const float* __restrict__ x, unsigned short* __restrict__ xb,
    const float* __restrict__ Wqkv, unsigned short* __restrict__ wqkvT,
    const float* __restrict__ Wout, unsigned short* __restrict__ woutT) {
    __shared__ float tile[32][33];
    const int bid = blockIdx.x;
    if (bid < 4096) {
        int i = bid * 256 + threadIdx.x;
        float4 v = ((const float4*)x)[i];
        ushort4 o;
        o.x = bfbits(v.x); o.y = bfbits(v.y);
        o.z = bfbits(v.z); o.w = bfbits(v.w);
        ((ushort4*)xb)[i] = o;
        return;
    }
    const float* W; unsigned short* Wt; int N, n0, k0;
    if (bid < 7168) {
        int l = bid - 4096; W = Wqkv; Wt = wqkvT; N = 3072;
        n0 = (l % 96) * 32; k0 = (l / 96) * 32;
    } else {
        int l = bid - 7168; W = Wout; Wt = woutT; N = 1024;
        n0 = (l & 31) * 32; k0 = (l >> 5) * 32;
    }
    int tx = threadIdx.x & 31, ty = threadIdx.x >> 5;
#pragma unroll
    for (int i = 0; i < 4; i++) {
        int r = ty + i * 8;
        tile[r][tx] = W[(size_t)(k0 + r) * N + n0 + tx];
    }
    __syncthreads();
#pragma unroll
    for (int i = 0; i < 4; i++) {
        int r = ty + i * 8;
        Wt[(size_t)(n0 + r) * 1024 + k0 + tx] = bfbits(tile[tx][r]);
    }
}

// ---------------------------------------------------------------- QKV GEMM
// R13: 64x128 tile (M x N), glds dbuf, grid 1536 = 6 blocks/CU. Per-wave
// 32x64 (acc[2][4]). V^T scattered in epilogue (R9 t-permute, R11
// ushort4-merged). XCD chunk: 192/XCD = 12n x 16m.
__global__ __launch_bounds__(256) void qkv_gemm_kernel(
    const unsigned short* __restrict__ A, const unsigned short* __restrict__ Bt,
    const float* __restrict__ bias, unsigned short* __restrict__ Qb,
    unsigned short* __restrict__ Kb, unsigned short* __restrict__ Vtb) {
    __shared__ unsigned short As[2][64 * 32];
    __shared__ unsigned short Bs[2][128 * 32];
    const int wg = blockIdx.x;                 // 0..1535
    const int xcd = wg & 7, local = wg >> 3;   // local 0..191
    const int n_t = (xcd >> 2) * 12 + local % 12;    // 0..23
    const int m_t = (xcd & 3) * 16 + local / 12;     // 0..63
    const int m0 = m_t * 64, n0 = n_t * 128;
    const int tid = threadIdx.x;
    const int lane = tid & 63, w = tid >> 6;
    const int ln = lane & 15, quad = lane >> 4;
    const int wm = (w >> 1) * 32, wn = (w & 1) * 64;
    const int sr = lane >> 2, sc = (lane & 3) * 8;
    f32x4 acc[2][4] = {};
    {
        int ra = w * 16;
        glds16(&A[(size_t)(m0 + ra + sr) * 1024 + sc], &As[0][ra * 32]);
#pragma unroll
        for (int i = 0; i < 2; i++) {
            int rb = w * 32 + i * 16;
            glds16(&Bt[(size_t)(n0 + rb + sr) * 1024 + sc], &Bs[0][rb * 32]);
        }
    }
    __syncthreads();
    for (int kt = 0; kt < 32; kt++) {
        const int cur = kt & 1;
        if (kt + 1 < 32) {
            const int nxt = cur ^ 1;
            const int kc = (kt + 1) * 32;
            int ra = w * 16;
            glds16(&A[(size_t)(m0 + ra + sr) * 1024 + kc + sc], &As[nxt][ra * 32]);
#pragma unroll
            for (int i = 0; i < 2; i++) {
                int rb = w * 32 + i * 16;
                glds16(&Bt[(size_t)(n0 + rb + sr) * 1024 + kc + sc], &Bs[nxt][rb * 32]);
            }
        }
        bf16x8 af[2], bf[4];
#pragma unroll
        for (int mi = 0; mi < 2; mi++)
            af[mi] = ld8(&As[cur][(wm + mi * 16 + ln) * 32 + quad * 8]);
#pragma unroll
        for (int ni = 0; ni < 4; ni++)
            bf[ni] = ld8(&Bs[cur][(wn + ni * 16 + ln) * 32 + quad * 8]);
#pragma unroll
        for (int mi = 0; mi < 2; mi++)
#pragma unroll
            for (int ni = 0; ni < 4; ni++)
                acc[mi][ni] = mfma32(af[mi], bf[ni], acc[mi][ni]);
        __syncthreads();
    }
#pragma unroll
    for (int mi = 0; mi < 2; mi++)
#pragma unroll
        for (int ni = 0; ni < 4; ni++) {
            int gn = n0 + wn + ni * 16 + ln;
            float bi = bias[gn];
            int h = gn / 192, rr = gn - h * 192;
            int gm0 = m0 + wm + mi * 16 + quad * 4;
            int b = gm0 >> 11, t0 = gm0 & 2047;
            float vv[4];
#pragma unroll
            for (int r = 0; r < 4; r++) vv[r] = acc[mi][ni][r] + bi;
            if (rr < 64) {
                size_t base = ((size_t)(b * 16 + h) * 2048 + t0) * 64 + rr;
#pragma unroll
                for (int r = 0; r < 4; r++)
                    Qb[base + (size_t)r * 64] = bfbits(vv[r] * QSCALE);
            } else if (rr < 128) {
                size_t base = ((size_t)(b * 16 + h) * 2048 + t0) * 64 + rr - 64;
#pragma unroll
                for (int r = 0; r < 4; r++)
                    Kb[base + (size_t)r * 64] = bfbits(vv[r]);
            } else {
                // R9 permute: t=16b'+4q+r -> 8q+4b'+r ; bit4 of t0 = mi&1
                // (wm multiples of 32) -> thread's 4 r-values tp-contiguous.
                int tp0 = (t0 & ~31) | (quad << 3) | ((mi & 1) << 2);
                ushort4 pk;
                pk.x = bfbits(vv[0]); pk.y = bfbits(vv[1]);
                pk.z = bfbits(vv[2]); pk.w = bfbits(vv[3]);
                *(ushort4*)&Vtb[((size_t)(b * 16 + h) * 64 + (rr - 128)) * 2048
                                + tp0] = pk;
            }
        }
}

// ---------------------------------------------------------------- attention
// One 512-thread block = both split-K halves (waves 0-3 ks=0, 4-7 ks=1),
// per-half 32KB LDS loop state; in-kernel combine via XOR-swizzled LDS
// exchange. Grid 512 = (bh,qt), XCD-chunked: 4 bh-panels per XCD.
// R12: raw v_exp_f32, pinned-zero MFMA C-init, v_rcp epilogue.
__global__ __launch_bounds__(512)
__attribute__((amdgpu_waves_per_eu(4, 4)))
void attn_kernel(
    const unsigned short* __restrict__ Q, const unsigned short* __restrict__ K,
    const unsigned short* __restrict__ Vt, unsigned short* __restrict__ Ob) {
    __shared__ unsigned short smem[2][2][2][4096];  // [ks][K/V][buf][64*64]
    const int wg  = blockIdx.x;                 // 0..511
    const int xcd = wg & 7, local = wg >> 3;    // local 0..63
    const int bh  = xcd * 4 + (local >> 4);     // 0..31 (4 bh per XCD)
    const int qt  = local & 15;
    const int tid = threadIdx.x;
    const int lane = tid & 63, w = tid >> 6;    // w 0..7
    const int w4 = w & 3, ks = w >> 2;
    const int ln = lane & 15, quad = lane >> 4;
    const int lr = lane >> 3, lg = lane & 7;
    const int e = ln & 7;

    unsigned short (*Ks)[4096] = smem[ks][0];   // [2][4096] dbuf contiguous
    unsigned short (*Vs)[4096] = smem[ks][1];

    const unsigned short* Qg = Q + ((size_t)bh * 2048 + qt * 128) * 64;
    const unsigned short* Kg = K + ((size_t)bh * 2048 + ks * 1024) * 64;
    const unsigned short* Vg = Vt + (size_t)bh * 64 * 2048 + ks * 1024;

    // Q fragments (B-operand: n=q=ln, k=d)
    bf16x8 qf[2][2];
#pragma unroll
    for (int h = 0; h < 2; h++) {
        const unsigned short* qp = Qg + (size_t)(w4 * 32 + h * 16 + ln) * 64;
        qf[h][0] = ld8(qp + quad * 8);
        qf[h][1] = ld8(qp + 32 + quad * 8);
    }

    // loop-invariant LDS compute-read bases (+ms*1024/+df*1024 and
    // +parity*4096 are constant offsets -> ds_read immediates)
    const unsigned short* kb0 = &Ks[0][ln * 64 + (quad ^ e) * 8];
    const unsigned short* kb1 = &Ks[0][ln * 64 + ((4 + quad) ^ e) * 8];
    const unsigned short* vp0 = &Vs[0][ln * 64 + (quad ^ e) * 8];
    const unsigned short* vp1 = &Vs[0][ln * 64 + ((4 + quad) ^ e) * 8];

    // loop-invariant staging offsets (lg^lr is lane-constant)
    const int kof0 = (w4 * 16 + lr) * 64 + (lg ^ lr) * 8;
    const int kof1 = (w4 * 16 + 8 + lr) * 64 + (lg ^ lr) * 8;
    const int vof0 = (w4 * 16 + lr) * 2048 + (lg ^ lr) * 8;
    const int vof1 = (w4 * 16 + 8 + lr) * 2048 + (lg ^ lr) * 8;
    unsigned short* kd0[2] = {&Ks[0][(w4 * 16) * 64], &Ks[1][(w4 * 16) * 64]};
    unsigned short* kd1[2] = {&Ks[0][(w4 * 16 + 8) * 64], &Ks[1][(w4 * 16 + 8) * 64]};
    unsigned short* vd0[2] = {&Vs[0][(w4 * 16) * 64], &Vs[1][(w4 * 16) * 64]};
    unsigned short* vd1[2] = {&Vs[0][(w4 * 16 + 8) * 64], &Vs[1][(w4 * 16 + 8) * 64]};

    // stage tile 0
    glds16(Kg + kof0, kd0[0]);
    glds16(Kg + kof1, kd1[0]);
    glds16(Vg + vof0, vd0[0]);
    glds16(Vg + vof1, vd1[0]);
    __syncthreads();

    const unsigned short* KgR = Kg + 4096;   // next K tile (64 rows x 64)
    const unsigned short* VgR = Vg + 64;     // next V tile (64 t-cols)

    bf16x8 ones8;
#pragma unroll
    for (int j = 0; j < 8; j++) ones8[j] = __bf16(1.0f);
    // R12: pinned zero C-operand (asm keep-alive prevents remat -> no
    // per-tile 32x v_mov zero-init of the s tiles).
    f32x4 zero4 = {};
    asm volatile("" : "+v"(zero4));
    f32x4 o[2][4] = {};
    f32x4 lacc[2] = {};

#define ATTN_TILE(CUR, PREF)                                                  \
    do {                                                                      \
        if (PREF) {                                                           \
            glds16(KgR + kof0, kd0[CUR ^ 1]);                                 \
            glds16(KgR + kof1, kd1[CUR ^ 1]);                                 \
            glds16(VgR + vof0, vd0[CUR ^ 1]);                                 \
            glds16(VgR + vof1, vd1[CUR ^ 1]);                                 \
            KgR += 4096; VgR += 64;                                           \
        }                                                                     \
        f32x4 s[2][4];                                                        \
        _Pragma("unroll")                                                     \
        for (int ms = 0; ms < 4; ms++) {                                      \
            bf16x8 a0 = ld8(kb0 + (CUR) * 4096 + ms * 1024);                  \
            bf16x8 a1 = ld8(kb1 + (CUR) * 4096 + ms * 1024);                  \
            _Pragma("unroll")                                                 \
            for (int h = 0; h < 2; h++) {                                     \
                s[h][ms] = mfma32(a0, qf[h][0], zero4);                       \
                s[h][ms] = mfma32(a1, qf[h][1], s[h][ms]);                    \
            }                                                                 \
        }                                                                     \
        bf16x8 pb8[2][2];                                                     \
        _Pragma("unroll")                                                     \
        for (int h = 0; h < 2; h++)                                           \
            _Pragma("unroll")                                                 \
            for (int p = 0; p < 2; p++) {                                     \
                f32x4 e0, e1;                                                 \
                e0[0] = EXP2(s[h][2 * p][0]); e0[1] = EXP2(s[h][2 * p][1]);   \
                e0[2] = EXP2(s[h][2 * p][2]); e0[3] = EXP2(s[h][2 * p][3]);   \
                e1[0] = EXP2(s[h][2 * p + 1][0]);                             \
                e1[1] = EXP2(s[h][2 * p + 1][1]);                             \
                e1[2] = EXP2(s[h][2 * p + 1][2]);                             \
                e1[3] = EXP2(s[h][2 * p + 1][3]);                             \
                pb8[h][p][0] = __bf16(e0[0]); pb8[h][p][1] = __bf16(e0[1]);   \
                pb8[h][p][2] = __bf16(e0[2]); pb8[h][p][3] = __bf16(e0[3]);   \
                pb8[h][p][4] = __bf16(e1[0]); pb8[h][p][5] = __bf16(e1[1]);   \
                pb8[h][p][6] = __bf16(e1[2]); pb8[h][p][7] = __bf16(e1[3]);   \
            }                                                                 \
        _Pragma("unroll")                                                     \
        for (int h = 0; h < 2; h++)                                           \
            _Pragma("unroll")                                                 \
            for (int p = 0; p < 2; p++)                                       \
                lacc[h] = mfma32(ones8, pb8[h][p], lacc[h]);                  \
        _Pragma("unroll")                                                     \
        for (int df = 0; df < 4; df++) {                                      \
            bf16x8 a80 = ld8(vp0 + (CUR) * 4096 + df * 1024);                 \
            o[0][df] = mfma32(a80, pb8[0][0], o[0][df]);                      \
            o[1][df] = mfma32(a80, pb8[1][0], o[1][df]);                      \
            bf16x8 a81 = ld8(vp1 + (CUR) * 4096 + df * 1024);                 \
            o[0][df] = mfma32(a81, pb8[0][1], o[0][df]);                      \
            o[1][df] = mfma32(a81, pb8[1][1], o[1][df]);                      \
        }                                                                     \
        __syncthreads();                                                      \
    } while (0)

    for (int it = 0; it < 8; it++) {
        ATTN_TILE(0, true);                 // tile 2*it, prefetch 2*it+1
        ATTN_TILE(1, (it < 7));             // tile 2*it+1, prefetch 2*it+2
    }
#undef ATTN_TILE

    // ---- in-kernel split-K combine (LDS exchange; loop LDS now dead).
    // XOR-swizzled 16B chunks: chunk = slot*8 + (j ^ (slot&7)) -> for fixed
    // j the 64 lanes' start banks cycle all 32 banks -> conflict-free.
    float* xf = (float*)&smem[0][0][0][0];
    const int slot = w4 * 64 + lane;            // 0..255
    if (ks) {
#pragma unroll
        for (int h = 0; h < 2; h++)
#pragma unroll
            for (int df = 0; df < 4; df++) {
                int j = h * 4 + df;
                *(f32x4*)(xf + (size_t)(slot * 8 + (j ^ (slot & 7))) * 4) = o[h][df];
            }
        xf[8192 + slot * 2 + 0] = lacc[0][0];
        xf[8192 + slot * 2 + 1] = lacc[1][0];
    }
    __syncthreads();
    if (!ks) {
        float inv0 = RCP(lacc[0][0] + xf[8192 + slot * 2 + 0]);
        float inv1 = RCP(lacc[1][0] + xf[8192 + slot * 2 + 1]);
        const int b = bh >> 4, hh = bh & 15;
#pragma unroll
        for (int h = 0; h < 2; h++) {
            float inv = h ? inv1 : inv0;
            int qrow = qt * 128 + w4 * 32 + h * 16 + ln;
            size_t row = ((size_t)b * 2048 + qrow) * 1024 + hh * 64;
#pragma unroll
            for (int df = 0; df < 4; df++) {
                int j = h * 4 + df;
                f32x4 oo = *(const f32x4*)(xf + (size_t)(slot * 8 + (j ^ (slot & 7))) * 4);
                ushort4 pk;
                pk.x = bfbits((o[h][df][0] + oo[0]) * inv);
                pk.y = bfbits((o[h][df][1] + oo[1]) * inv);
                pk.z = bfbits((o[h][df][2] + oo[2]) * inv);
                pk.w = bfbits((o[h][df][3] + oo[3]) * inv);
                *(ushort4*)&Ob[row + df * 16 + quad * 4] = pk;
            }
        }
    }
}

// ---------------------------------------------------------------- out GEMM
// R11: 64x128 tile (M x N), glds dbuf. Grid 512 = 2 blocks/CU. Per-wave
// 32x64. XCD-chunked: each XCD owns 8 consecutive m-tiles x all 8 n-tiles.
__global__ __launch_bounds__(256) void out_gemm_kernel(
    const unsigned short* __restrict__ A, const unsigned short* __restrict__ Bt,
    const float* __restrict__ bias, float* __restrict__ out) {
    __shared__ unsigned short As[2][64 * 32];
    __shared__ unsigned short Bs[2][128 * 32];
    const int wg = blockIdx.x;                 // 0..511
    const int xcd = wg & 7, local = wg >> 3;   // local 0..63
    const int m_t = xcd * 8 + (local & 7);     // 0..63
    const int n_t = local >> 3;                // 0..7
    const int m0 = m_t * 64, n0 = n_t * 128;
    const int tid = threadIdx.x;
    const int lane = tid & 63, w = tid >> 6;
    const int ln = lane & 15, quad = lane >> 4;
    const int wm = (w >> 1) * 32, wn = (w & 1) * 64;
    const int sr = lane >> 2, sc = (lane & 3) * 8;
    f32x4 acc[2][4] = {};
    {
        int ra = w * 16;
        glds16(&A[(size_t)(m0 + ra + sr) * 1024 + sc], &As[0][ra * 32]);
#pragma unroll
        for (int i = 0; i < 2; i++) {
            int rb = w * 32 + i * 16;
            glds16(&Bt[(size_t)(n0 + rb + sr) * 1024 + sc], &Bs[0][rb * 32]);
        }
    }
    __syncthreads();
    for (int kt = 0; kt < 32; kt++) {
        const int cur = kt & 1;
        if (kt + 1 < 32) {
            const int nxt = cur ^ 1;
            const int kc = (kt + 1) * 32;
            int ra = w * 16;
            glds16(&A[(size_t)(m0 + ra + sr) * 1024 + kc + sc], &As[nxt][ra * 32]);
#pragma unroll
            for (int i = 0; i < 2; i++) {
                int rb = w * 32 + i * 16;
                glds16(&Bt[(size_t)(n0 + rb + sr) * 1024 + kc + sc], &Bs[nxt][rb * 32]);
            }
        }
        bf16x8 af[2], bf[4];
#pragma unroll
        for (int mi = 0; mi < 2; mi++)
            af[mi] = ld8(&As[cur][(wm + mi * 16 + ln) * 32 + quad * 8]);
#pragma unroll
        for (int ni = 0; ni < 4; ni++)
            bf[ni] = ld8(&Bs[cur][(wn + ni * 16 + ln) * 32 + quad * 8]);
#pragma unroll
        for (int mi = 0; mi < 2; mi++)
#pragma unroll
            for (int ni = 0; ni < 4; ni++)
                acc[mi][ni] = mfma32(af[mi], bf[ni], acc[mi][ni]);
        __syncthreads();
    }
#pragma unroll
    for (int mi = 0; mi < 2; mi++)
#pragma unroll
        for (int ni = 0; ni < 4; ni++) {
            int gn = n0 + wn + ni * 16 + ln;
            float bi = bias[gn];
#pragma unroll
            for (int r = 0; r < 4; r++) {
                int gm = m0 + wm + mi * 16 + quad * 4 + r;
                out[(size_t)gm * 1024 + gn] = acc[mi][ni][r] + bi;
            }
        }
}

// ---------------------------------------------------------------------------
extern "C" void kernel_launch(void* const* d_in, const int* in_sizes, int n_in,
                              void* d_out, int out_size, void* d_ws, size_t ws_size,
                              hipStream_t stream) {
    const float* x     = (const float*)d_in[0];
    const float* W_qkv = (const float*)d_in[1];
    const float* b_qkv = (const float*)d_in[2];
    const float* W_out = (const float*)d_in[3];
    const float* b_out = (const float*)d_in[4];
    float* out = (float*)d_out;

    char* ws = (char*)d_ws;                            // 48 MB total footprint
    unsigned short* xb    = (unsigned short*)(ws);                      // 8 MB
    unsigned short* wqkvT = (unsigned short*)(ws + (size_t)( 8 << 20)); // 6 MB
    unsigned short* woutT = (unsigned short*)(ws + (size_t)(14 << 20)); // 2 MB
    unsigned short* Qb    = (unsigned short*)(ws + (size_t)(16 << 20)); // 8 MB
    unsigned short* Kb    = (unsigned short*)(ws + (size_t)(24 << 20)); // 8 MB
    unsigned short* Vtb   = (unsigned short*)(ws + (size_t)(32 << 20)); // 8 MB
    unsigned short* attnb = (unsigned short*)(ws + (size_t)(40 << 20)); // 8 MB

    prep_kernel<<<8192, 256, 0, stream>>>(x, xb, W_qkv, wqkvT, W_out, woutT);
    qkv_gemm_kernel<<<1536, 256, 0, stream>>>(xb, wqkvT, b_qkv, Qb, Kb, Vtb);
    attn_kernel<<<512, 512, 0, stream>>>(Qb, Kb, Vtb, attnb);
    out_gemm_kernel<<<512, 256, 0, stream>>>(attnb, woutT, b_out, out);
}

// Round 10
// 185.875 us; speedup vs baseline: 1.0374x; 1.0374x over previous
//
#include <hip/hip_runtime.h>

// ---------------------------------------------------------------------------
// MultiHeadAttention: B=2, T=2048, C=1024, H=16, D=64
// prep (cast x -> bf16 ; transpose W_qkv, W_out -> bf16 [N][K], fused) ;
// QKV GEMM -> Q (prescaled 0.125*log2e), K [b,h,t,d], V^T [b,h,d,t] ;
// flash attention (fixed-base softmax), Q in regs, K/V glds dbuf
// XOR-swizzled LDS, precomputed bases, kt unrolled x2.
// R6: PV + row-sum packed into mfma_f32_16x16x32 (K=32), 36 MFMA/tile.
// R7: XCD-chunked swizzle (FETCH 73.8 -> 20.6 MB measured).
// R9: Vtb t-axis pre-permuted => PV A-operand is one ds_read_b128; bank
// conflicts 4.19M -> 0 (measured).
// R10: split-K fused into one 512-thread block, in-kernel LDS combine.
// R11: out GEMM 64x128 (2 blocks/CU); qkv V^T ushort4 stores; prep fused.
// R12: attn VALU diet: raw v_exp_f32, pinned zero4 C-init, v_rcp.
// R13 REGRESSED (qkv 64x128: FETCH 20.6->33.3MB, MfmaUtil 15.7% — tile
// shrink killed B-reuse; occupancy was not the binding constraint).
// R14: qkv back to 128x128 tile but with 512 threads / 8 waves (4m x 2n,
// per-wave 32x64): same tile reuse + traffic as R12, but 24 waves/CU =
// 6 waves/SIMD (vs 3) to hide the per-kt barrier drain. Staging = exactly
// 1 A + 1 B glds16 per thread (8KB = 512x16B, linear dest).
// ---------------------------------------------------------------------------

typedef float  f32x4  __attribute__((ext_vector_type(4)));
typedef __bf16 bf16x8 __attribute__((ext_vector_type(8)));

#define QSCALE 0.18033688011112042f   // 0.125 * log2(e)

#if __has_builtin(__builtin_amdgcn_exp2f)
#define EXP2(x) __builtin_amdgcn_exp2f(x)
#else
#define EXP2(x) exp2f(x)
#endif
#if __has_builtin(__builtin_amdgcn_rcpf)
#define RCP(x) __builtin_amdgcn_rcpf(x)
#else
#define RCP(x) (1.0f / (x))
#endif

static __device__ __forceinline__ f32x4 mfma32(bf16x8 a, bf16x8 b, f32x4 c) {
    return __builtin_amdgcn_mfma_f32_16x16x32_bf16(a, b, c, 0, 0, 0);
}

static __device__ __forceinline__ bf16x8 ld8(const unsigned short* p) {
    return __builtin_bit_cast(bf16x8, *(const uint4*)p);
}
static __device__ __forceinline__ unsigned short bfbits(float f) {
    __bf16 h = (__bf16)f;
    return __builtin_bit_cast(unsigned short, h);
}

static __device__ __forceinline__ void glds16(const unsigned short* g,
                                              unsigned short* lds_base) {
    __builtin_amdgcn_global_load_lds(
        (const __attribute__((address_space(1))) unsigned int*)g,
        (__attribute__((address_space(3))) unsigned int*)lds_base, 16, 0, 0);
}

// ------------------------------------------------------------ prep (fused)
// blocks [0,4096): cast x -> bf16 (float4/ushort4)
// blocks [4096,7168): transpose+cast W_qkv (96x32 tiles of 32x32)
// blocks [7168,8192): transpose+cast W_out (32x32 tiles)
__global__ __launch_bounds__(256) void prep_kernel(
    const float* __restrict__ x, unsigned short* __restrict__ xb,
    const float* __restrict__ Wqkv, unsigned short* __restrict__ wqkvT,
    const float* __restrict__ Wout, unsigned short* __restrict__ woutT) {
    __shared__ float tile[32][33];
    const int bid = blockIdx.x;
    if (bid < 4096) {
        int i = bid * 256 + threadIdx.x;
        float4 v = ((const float4*)x)[i];
        ushort4 o;
        o.x = bfbits(v.x); o.y = bfbits(v.y);
        o.z = bfbits(v.z); o.w = bfbits(v.w);
        ((ushort4*)xb)[i] = o;
        return;
    }
    const float* W; unsigned short* Wt; int N, n0, k0;
    if (bid < 7168) {
        int l = bid - 4096; W = Wqkv; Wt = wqkvT; N = 3072;
        n0 = (l % 96) * 32; k0 = (l / 96) * 32;
    } else {
        int l = bid - 7168; W = Wout; Wt = woutT; N = 1024;
        n0 = (l & 31) * 32; k0 = (l >> 5) * 32;
    }
    int tx = threadIdx.x & 31, ty = threadIdx.x >> 5;
#pragma unroll
    for (int i = 0; i < 4; i++) {
        int r = ty + i * 8;
        tile[r][tx] = W[(size_t)(k0 + r) * N + n0 + tx];
    }
    __syncthreads();
#pragma unroll
    for (int i = 0; i < 4; i++) {
        int r = ty + i * 8;
        Wt[(size_t)(n0 + r) * 1024 + k0 + tx] = bfbits(tile[tx][r]);
    }
}

// ---------------------------------------------------------------- QKV GEMM
// R14: 128x128 tile, 512 threads / 8 waves (4m x 2n, per-wave 32x64,
// acc[2][4]). glds dbuf; grid 768 = 3 blocks/CU = 6 waves/SIMD. V^T
// scattered in epilogue (R9 t-permute, R11 ushort4). XCD chunk 12n x 8m.
__global__ __launch_bounds__(512) void qkv_gemm_kernel(
    const unsigned short* __restrict__ A, const unsigned short* __restrict__ Bt,
    const float* __restrict__ bias, unsigned short* __restrict__ Qb,
    unsigned short* __restrict__ Kb, unsigned short* __restrict__ Vtb) {
    __shared__ unsigned short As[2][128 * 32];
    __shared__ unsigned short Bs[2][128 * 32];
    const int wg = blockIdx.x;                 // 0..767
    const int xcd = wg & 7, local = wg >> 3;   // local 0..95
    const int n_t = (xcd >> 2) * 12 + local % 12;   // 0..23
    const int m_t = (xcd & 3) * 8 + local / 12;     // 0..31
    const int m0 = m_t * 128, n0 = n_t * 128;
    const int tid = threadIdx.x;
    const int lane = tid & 63, w = tid >> 6;   // w 0..7
    const int ln = lane & 15, quad = lane >> 4;
    const int wm = (w >> 1) * 32, wn = (w & 1) * 64;
    const int srow = tid >> 2;                 // 0..127
    const int scol = (tid & 3) * 8;
    f32x4 acc[2][4] = {};
    glds16(&A[(size_t)(m0 + srow) * 1024 + scol], &As[0][(w * 16) * 32]);
    glds16(&Bt[(size_t)(n0 + srow) * 1024 + scol], &Bs[0][(w * 16) * 32]);
    __syncthreads();
    for (int kt = 0; kt < 32; kt++) {
        const int cur = kt & 1;
        if (kt + 1 < 32) {
            const int nxt = cur ^ 1;
            const int kc = (kt + 1) * 32;
            glds16(&A[(size_t)(m0 + srow) * 1024 + kc + scol], &As[nxt][(w * 16) * 32]);
            glds16(&Bt[(size_t)(n0 + srow) * 1024 + kc + scol], &Bs[nxt][(w * 16) * 32]);
        }
        bf16x8 af[2], bf[4];
#pragma unroll
        for (int mi = 0; mi < 2; mi++)
            af[mi] = ld8(&As[cur][(wm + mi * 16 + ln) * 32 + quad * 8]);
#pragma unroll
        for (int ni = 0; ni < 4; ni++)
            bf[ni] = ld8(&Bs[cur][(wn + ni * 16 + ln) * 32 + quad * 8]);
#pragma unroll
        for (int mi = 0; mi < 2; mi++)
#pragma unroll
            for (int ni = 0; ni < 4; ni++)
                acc[mi][ni] = mfma32(af[mi], bf[ni], acc[mi][ni]);
        __syncthreads();
    }
#pragma unroll
    for (int mi = 0; mi < 2; mi++)
#pragma unroll
        for (int ni = 0; ni < 4; ni++) {
            int gn = n0 + wn + ni * 16 + ln;
            float bi = bias[gn];
            int h = gn / 192, rr = gn - h * 192;
            int gm0 = m0 + wm + mi * 16 + quad * 4;
            int b = gm0 >> 11, t0 = gm0 & 2047;
            float vv[4];
#pragma unroll
            for (int r = 0; r < 4; r++) vv[r] = acc[mi][ni][r] + bi;
            if (rr < 64) {
                size_t base = ((size_t)(b * 16 + h) * 2048 + t0) * 64 + rr;
#pragma unroll
                for (int r = 0; r < 4; r++)
                    Qb[base + (size_t)r * 64] = bfbits(vv[r] * QSCALE);
            } else if (rr < 128) {
                size_t base = ((size_t)(b * 16 + h) * 2048 + t0) * 64 + rr - 64;
#pragma unroll
                for (int r = 0; r < 4; r++)
                    Kb[base + (size_t)r * 64] = bfbits(vv[r]);
            } else {
                // R9 permute: t=16b'+4q+r -> 8q+4b'+r ; bit4 of t0 = mi&1
                // (wm multiples of 32) -> thread's 4 r-values tp-contiguous.
                int tp0 = (t0 & ~31) | (quad << 3) | ((mi & 1) << 2);
                ushort4 pk;
                pk.x = bfbits(vv[0]); pk.y = bfbits(vv[1]);
                pk.z = bfbits(vv[2]); pk.w = bfbits(vv[3]);
                *(ushort4*)&Vtb[((size_t)(b * 16 + h) * 64 + (rr - 128)) * 2048
                                + tp0] = pk;
            }
        }
}

// ---------------------------------------------------------------- attention
// One 512-thread block = both split-K halves (waves 0-3 ks=0, 4-7 ks=1),
// per-half 32KB LDS loop state; in-kernel combine via XOR-swizzled LDS
// exchange. Grid 512 = (bh,qt), XCD-chunked: 4 bh-panels per XCD.
// R12: raw v_exp_f32, pinned-zero MFMA C-init, v_rcp epilogue.
__global__ __launch_bounds__(512)
__attribute__((amdgpu_waves_per_eu(4, 4)))
void attn_kernel(
    const unsigned short* __restrict__ Q, const unsigned short* __restrict__ K,
    const unsigned short* __restrict__ Vt, unsigned short* __restrict__ Ob) {
    __shared__ unsigned short smem[2][2][2][4096];  // [ks][K/V][buf][64*64]
    const int wg  = blockIdx.x;                 // 0..511
    const int xcd = wg & 7, local = wg >> 3;    // local 0..63
    const int bh  = xcd * 4 + (local >> 4);     // 0..31 (4 bh per XCD)
    const int qt  = local & 15;
    const int tid = threadIdx.x;
    const int lane = tid & 63, w = tid >> 6;    // w 0..7
    const int w4 = w & 3, ks = w >> 2;
    const int ln = lane & 15, quad = lane >> 4;
    const int lr = lane >> 3, lg = lane & 7;
    const int e = ln & 7;

    unsigned short (*Ks)[4096] = smem[ks][0];   // [2][4096] dbuf contiguous
    unsigned short (*Vs)[4096] = smem[ks][1];

    const unsigned short* Qg = Q + ((size_t)bh * 2048 + qt * 128) * 64;
    const unsigned short* Kg = K + ((size_t)bh * 2048 + ks * 1024) * 64;
    const unsigned short* Vg = Vt + (size_t)bh * 64 * 2048 + ks * 1024;

    // Q fragments (B-operand: n=q=ln, k=d)
    bf16x8 qf[2][2];
#pragma unroll
    for (int h = 0; h < 2; h++) {
        const unsigned short* qp = Qg + (size_t)(w4 * 32 + h * 16 + ln) * 64;
        qf[h][0] = ld8(qp + quad * 8);
        qf[h][1] = ld8(qp + 32 + quad * 8);
    }

    // loop-invariant LDS compute-read bases (+ms*1024/+df*1024 and
    // +parity*4096 are constant offsets -> ds_read immediates)
    const unsigned short* kb0 = &Ks[0][ln * 64 + (quad ^ e) * 8];
    const unsigned short* kb1 = &Ks[0][ln * 64 + ((4 + quad) ^ e) * 8];
    const unsigned short* vp0 = &Vs[0][ln * 64 + (quad ^ e) * 8];
    const unsigned short* vp1 = &Vs[0][ln * 64 + ((4 + quad) ^ e) * 8];

    // loop-invariant staging offsets (lg^lr is lane-constant)
    const int kof0 = (w4 * 16 + lr) * 64 + (lg ^ lr) * 8;
    const int kof1 = (w4 * 16 + 8 + lr) * 64 + (lg ^ lr) * 8;
    const int vof0 = (w4 * 16 + lr) * 2048 + (lg ^ lr) * 8;
    const int vof1 = (w4 * 16 + 8 + lr) * 2048 + (lg ^ lr) * 8;
    unsigned short* kd0[2] = {&Ks[0][(w4 * 16) * 64], &Ks[1][(w4 * 16) * 64]};
    unsigned short* kd1[2] = {&Ks[0][(w4 * 16 + 8) * 64], &Ks[1][(w4 * 16 + 8) * 64]};
    unsigned short* vd0[2] = {&Vs[0][(w4 * 16) * 64], &Vs[1][(w4 * 16) * 64]};
    unsigned short* vd1[2] = {&Vs[0][(w4 * 16 + 8) * 64], &Vs[1][(w4 * 16 + 8) * 64]};

    // stage tile 0
    glds16(Kg + kof0, kd0[0]);
    glds16(Kg + kof1, kd1[0]);
    glds16(Vg + vof0, vd0[0]);
    glds16(Vg + vof1, vd1[0]);
    __syncthreads();

    const unsigned short* KgR = Kg + 4096;   // next K tile (64 rows x 64)
    const unsigned short* VgR = Vg + 64;     // next V tile (64 t-cols)

    bf16x8 ones8;
#pragma unroll
    for (int j = 0; j < 8; j++) ones8[j] = __bf16(1.0f);
    // R12: pinned zero C-operand (asm keep-alive prevents remat -> no
    // per-tile 32x v_mov zero-init of the s tiles).
    f32x4 zero4 = {};
    asm volatile("" : "+v"(zero4));
    f32x4 o[2][4] = {};
    f32x4 lacc[2] = {};

#define ATTN_TILE(CUR, PREF)                                                  \
    do {                                                                      \
        if (PREF) {                                                           \
            glds16(KgR + kof0, kd0[CUR ^ 1]);                                 \
            glds16(KgR + kof1, kd1[CUR ^ 1]);                                 \
            glds16(VgR + vof0, vd0[CUR ^ 1]);                                 \
            glds16(VgR + vof1, vd1[CUR ^ 1]);                                 \
            KgR += 4096; VgR += 64;                                           \
        }                                                                     \
        f32x4 s[2][4];                                                        \
        _Pragma("unroll")                                                     \
        for (int ms = 0; ms < 4; ms++) {                                      \
            bf16x8 a0 = ld8(kb0 + (CUR) * 4096 + ms * 1024);                  \
            bf16x8 a1 = ld8(kb1 + (CUR) * 4096 + ms * 1024);                  \
            _Pragma("unroll")                                                 \
            for (int h = 0; h < 2; h++) {                                     \
                s[h][ms] = mfma32(a0, qf[h][0], zero4);                       \
                s[h][ms] = mfma32(a1, qf[h][1], s[h][ms]);                    \
            }                                                                 \
        }                                                                     \
        bf16x8 pb8[2][2];                                                     \
        _Pragma("unroll")                                                     \
        for (int h = 0; h < 2; h++)                                           \
            _Pragma("unroll")                                                 \
            for (int p = 0; p < 2; p++) {                                     \
                f32x4 e0, e1;                                                 \
                e0[0] = EXP2(s[h][2 * p][0]); e0[1] = EXP2(s[h][2 * p][1]);   \
                e0[2] = EXP2(s[h][2 * p][2]); e0[3] = EXP2(s[h][2 * p][3]);   \
                e1[0] = EXP2(s[h][2 * p + 1][0]);                             \
                e1[1] = EXP2(s[h][2 * p + 1][1]);                             \
                e1[2] = EXP2(s[h][2 * p + 1][2]);                             \
                e1[3] = EXP2(s[h][2 * p + 1][3]);                             \
                pb8[h][p][0] = __bf16(e0[0]); pb8[h][p][1] = __bf16(e0[1]);   \
                pb8[h][p][2] = __bf16(e0[2]); pb8[h][p][3] = __bf16(e0[3]);   \
                pb8[h][p][4] = __bf16(e1[0]); pb8[h][p][5] = __bf16(e1[1]);   \
                pb8[h][p][6] = __bf16(e1[2]); pb8[h][p][7] = __bf16(e1[3]);   \
            }                                                                 \
        _Pragma("unroll")                                                     \
        for (int h = 0; h < 2; h++)                                           \
            _Pragma("unroll")                                                 \
            for (int p = 0; p < 2; p++)                                       \
                lacc[h] = mfma32(ones8, pb8[h][p], lacc[h]);                  \
        _Pragma("unroll")                                                     \
        for (int df = 0; df < 4; df++) {                                      \
            bf16x8 a80 = ld8(vp0 + (CUR) * 4096 + df * 1024);                 \
            o[0][df] = mfma32(a80, pb8[0][0], o[0][df]);                      \
            o[1][df] = mfma32(a80, pb8[1][0], o[1][df]);                      \
            bf16x8 a81 = ld8(vp1 + (CUR) * 4096 + df * 1024);                 \
            o[0][df] = mfma32(a81, pb8[0][1], o[0][df]);                      \
            o[1][df] = mfma32(a81, pb8[1][1], o[1][df]);                      \
        }                                                                     \
        __syncthreads();                                                      \
    } while (0)

    for (int it = 0; it < 8; it++) {
        ATTN_TILE(0, true);                 // tile 2*it, prefetch 2*it+1
        ATTN_TILE(1, (it < 7));             // tile 2*it+1, prefetch 2*it+2
    }
#undef ATTN_TILE

    // ---- in-kernel split-K combine (LDS exchange; loop LDS now dead).
    // XOR-swizzled 16B chunks: chunk = slot*8 + (j ^ (slot&7)) -> for fixed
    // j the 64 lanes' start banks cycle all 32 banks -> conflict-free.
    float* xf = (float*)&smem[0][0][0][0];
    const int slot = w4 * 64 + lane;            // 0..255
    if (ks) {
#pragma unroll
        for (int h = 0; h < 2; h++)
#pragma unroll
            for (int df = 0; df < 4; df++) {
                int j = h * 4 + df;
                *(f32x4*)(xf + (size_t)(slot * 8 + (j ^ (slot & 7))) * 4) = o[h][df];
            }
        xf[8192 + slot * 2 + 0] = lacc[0][0];
        xf[8192 + slot * 2 + 1] = lacc[1][0];
    }
    __syncthreads();
    if (!ks) {
        float inv0 = RCP(lacc[0][0] + xf[8192 + slot * 2 + 0]);
        float inv1 = RCP(lacc[1][0] + xf[8192 + slot * 2 + 1]);
        const int b = bh >> 4, hh = bh & 15;
#pragma unroll
        for (int h = 0; h < 2; h++) {
            float inv = h ? inv1 : inv0;
            int qrow = qt * 128 + w4 * 32 + h * 16 + ln;
            size_t row = ((size_t)b * 2048 + qrow) * 1024 + hh * 64;
#pragma unroll
            for (int df = 0; df < 4; df++) {
                int j = h * 4 + df;
                f32x4 oo = *(const f32x4*)(xf + (size_t)(slot * 8 + (j ^ (slot & 7))) * 4);
                ushort4 pk;
                pk.x = bfbits((o[h][df][0] + oo[0]) * inv);
                pk.y = bfbits((o[h][df][1] + oo[1]) * inv);
                pk.z = bfbits((o[h][df][2] + oo[2]) * inv);
                pk.w = bfbits((o[h][df][3] + oo[3]) * inv);
                *(ushort4*)&Ob[row + df * 16 + quad * 4] = pk;
            }
        }
    }
}

// ---------------------------------------------------------------- out GEMM
// R11: 64x128 tile (M x N), glds dbuf. Grid 512 = 2 blocks/CU. Per-wave
// 32x64. XCD-chunked: each XCD owns 8 consecutive m-tiles x all 8 n-tiles.
__global__ __launch_bounds__(256) void out_gemm_kernel(
    const unsigned short* __restrict__ A, const unsigned short* __restrict__ Bt,
    const float* __restrict__ bias, float* __restrict__ out) {
    __shared__ unsigned short As[2][64 * 32];
    __shared__ unsigned short Bs[2][128 * 32];
    const int wg = blockIdx.x;                 // 0..511
    const int xcd = wg & 7, local = wg >> 3;   // local 0..63
    const int m_t = xcd * 8 + (local & 7);     // 0..63
    const int n_t = local >> 3;                // 0..7
    const int m0 = m_t * 64, n0 = n_t * 128;
    const int tid = threadIdx.x;
    const int lane = tid & 63, w = tid >> 6;
    const int ln = lane & 15, quad = lane >> 4;
    const int wm = (w >> 1) * 32, wn = (w & 1) * 64;
    const int sr = lane >> 2, sc = (lane & 3) * 8;
    f32x4 acc[2][4] = {};
    {
        int ra = w * 16;
        glds16(&A[(size_t)(m0 + ra + sr) * 1024 + sc], &As[0][ra * 32]);
#pragma unroll
        for (int i = 0; i < 2; i++) {
            int rb = w * 32 + i * 16;
            glds16(&Bt[(size_t)(n0 + rb + sr) * 1024 + sc], &Bs[0][rb * 32]);
        }
    }
    __syncthreads();
    for (int kt = 0; kt < 32; kt++) {
        const int cur = kt & 1;
        if (kt + 1 < 32) {
            const int nxt = cur ^ 1;
            const int kc = (kt + 1) * 32;
            int ra = w * 16;
            glds16(&A[(size_t)(m0 + ra + sr) * 1024 + kc + sc], &As[nxt][ra * 32]);
#pragma unroll
            for (int i = 0; i < 2; i++) {
                int rb = w * 32 + i * 16;
                glds16(&Bt[(size_t)(n0 + rb + sr) * 1024 + kc + sc], &Bs[nxt][rb * 32]);
            }
        }
        bf16x8 af[2], bf[4];
#pragma unroll
        for (int mi = 0; mi < 2; mi++)
            af[mi] = ld8(&As[cur][(wm + mi * 16 + ln) * 32 + quad * 8]);
#pragma unroll
        for (int ni = 0; ni < 4; ni++)
            bf[ni] = ld8(&Bs[cur][(wn + ni * 16 + ln) * 32 + quad * 8]);
#pragma unroll
        for (int mi = 0; mi < 2; mi++)
#pragma unroll
            for (int ni = 0; ni < 4; ni++)
                acc[mi][ni] = mfma32(af[mi], bf[ni], acc[mi][ni]);
        __syncthreads();
    }
#pragma unroll
    for (int mi = 0; mi < 2; mi++)
#pragma unroll
        for (int ni = 0; ni < 4; ni++) {
            int gn = n0 + wn + ni * 16 + ln;
            float bi = bias[gn];
#pragma unroll
            for (int r = 0; r < 4; r++) {
                int gm = m0 + wm + mi * 16 + quad * 4 + r;
                out[(size_t)gm * 1024 + gn] = acc[mi][ni][r] + bi;
            }
        }
}

// ---------------------------------------------------------------------------
extern "C" void kernel_launch(void* const* d_in, const int* in_sizes, int n_in,
                              void* d_out, int out_size, void* d_ws, size_t ws_size,
                              hipStream_t stream) {
    const float* x     = (const float*)d_in[0];
    const float* W_qkv = (const float*)d_in[1];
    const float* b_qkv = (const float*)d_in[2];
    const float* W_out = (const float*)d_in[3];
    const float* b_out = (const float*)d_in[4];
    float* out = (float*)d_out;

    char* ws = (char*)d_ws;                            // 48 MB total footprint
    unsigned short* xb    = (unsigned short*)(ws);                      // 8 MB
    unsigned short* wqkvT = (unsigned short*)(ws + (size_t)( 8 << 20)); // 6 MB
    unsigned short* woutT = (unsigned short*)(ws + (size_t)(14 << 20)); // 2 MB
    unsigned short* Qb    = (unsigned short*)(ws + (size_t)(16 << 20)); // 8 MB
    unsigned short* Kb    = (unsigned short*)(ws + (size_t)(24 << 20)); // 8 MB
    unsigned short* Vtb   = (unsigned short*)(ws + (size_t)(32 << 20)); // 8 MB
    unsigned short* attnb = (unsigned short*)(ws + (size_t)(40 << 20)); // 8 MB

    prep_kernel<<<8192, 256, 0, stream>>>(x, xb, W_qkv, wqkvT, W_out, woutT);
    qkv_gemm_kernel<<<768, 512, 0, stream>>>(xb, wqkvT, b_qkv, Qb, Kb, Vtb);
    attn_kernel<<<512, 512, 0, stream>>>(Qb, Kb, Vtb, attnb);
    out_gemm_kernel<<<512, 256, 0, stream>>>(attnb, woutT, b_out, out);
}

// Round 11
// 177.035 us; speedup vs baseline: 1.0892x; 1.0499x over previous
//
#include <hip/hip_runtime.h>

// ---------------------------------------------------------------------------
// MultiHeadAttention: B=2, T=2048, C=1024, H=16, D=64
// prep (cast x -> bf16 ; transpose W_qkv, W_out -> bf16 [N][K], fused) ;
// QKV GEMM -> Q (prescaled 0.125*log2e), K [b,h,t,d], V^T [b,h,d,t] ;
// flash attention (fixed-base softmax), Q in regs, K/V glds dbuf
// XOR-swizzled LDS, precomputed bases, kt unrolled x2.
// R6: PV + row-sum packed into mfma_f32_16x16x32 (K=32), 36 MFMA/tile.
// R7: XCD-chunked swizzle (FETCH 73.8 -> 20.6 MB measured).
// R9: Vtb t-axis pre-permuted => PV A-operand is one ds_read_b128; bank
// conflicts 4.19M -> 0 (measured).
// R10: split-K fused into one 512-thread block, in-kernel LDS combine.
// R11: out GEMM 64x128 (2 blocks/CU); qkv V^T ushort4 stores; prep fused.
// R12: attn VALU diet: raw v_exp_f32, pinned zero4 C-init, v_rcp.
// R13/R14 REGRESSED (qkv 64x128 grid-6/CU: FETCH +60%, MfmaUtil 15.7%;
// qkv 128x128 8-wave 32x64/wave: 52.7us, 1.5x LDS traffic). Lesson: the
// per-wave 64x64 tile + 128^2 block of R12 is the optimum of this 2-barrier
// structure; occupancy is not the binding constraint.
// R15: qkv reverted VERBATIM to the R12-measured best (44.5us). attn: T5
// s_setprio(1) around MFMA clusters (phase-diverse 8-wave structure;
// correctness-neutral hint).
// ---------------------------------------------------------------------------

typedef float  f32x4  __attribute__((ext_vector_type(4)));
typedef __bf16 bf16x8 __attribute__((ext_vector_type(8)));

#define QSCALE 0.18033688011112042f   // 0.125 * log2(e)

#if __has_builtin(__builtin_amdgcn_exp2f)
#define EXP2(x) __builtin_amdgcn_exp2f(x)
#else
#define EXP2(x) exp2f(x)
#endif
#if __has_builtin(__builtin_amdgcn_rcpf)
#define RCP(x) __builtin_amdgcn_rcpf(x)
#else
#define RCP(x) (1.0f / (x))
#endif

static __device__ __forceinline__ f32x4 mfma32(bf16x8 a, bf16x8 b, f32x4 c) {
    return __builtin_amdgcn_mfma_f32_16x16x32_bf16(a, b, c, 0, 0, 0);
}

static __device__ __forceinline__ bf16x8 ld8(const unsigned short* p) {
    return __builtin_bit_cast(bf16x8, *(const uint4*)p);
}
static __device__ __forceinline__ unsigned short bfbits(float f) {
    __bf16 h = (__bf16)f;
    return __builtin_bit_cast(unsigned short, h);
}

static __device__ __forceinline__ void glds16(const unsigned short* g,
                                              unsigned short* lds_base) {
    __builtin_amdgcn_global_load_lds(
        (const __attribute__((address_space(1))) unsigned int*)g,
        (__attribute__((address_space(3))) unsigned int*)lds_base, 16, 0, 0);
}

// ------------------------------------------------------------ prep (fused)
// blocks [0,4096): cast x -> bf16 (float4/ushort4)
// blocks [4096,7168): transpose+cast W_qkv (96x32 tiles of 32x32)
// blocks [7168,8192): transpose+cast W_out (32x32 tiles)
__global__ __launch_bounds__(256) void prep_kernel(
    const float* __restrict__ x, unsigned short* __restrict__ xb,
    const float* __restrict__ Wqkv, unsigned short* __restrict__ wqkvT,
    const float* __restrict__ Wout, unsigned short* __restrict__ woutT) {
    __shared__ float tile[32][33];
    const int bid = blockIdx.x;
    if (bid < 4096) {
        int i = bid * 256 + threadIdx.x;
        float4 v = ((const float4*)x)[i];
        ushort4 o;
        o.x = bfbits(v.x); o.y = bfbits(v.y);
        o.z = bfbits(v.z); o.w = bfbits(v.w);
        ((ushort4*)xb)[i] = o;
        return;
    }
    const float* W; unsigned short* Wt; int N, n0, k0;
    if (bid < 7168) {
        int l = bid - 4096; W = Wqkv; Wt = wqkvT; N = 3072;
        n0 = (l % 96) * 32; k0 = (l / 96) * 32;
    } else {
        int l = bid - 7168; W = Wout; Wt = woutT; N = 1024;
        n0 = (l & 31) * 32; k0 = (l >> 5) * 32;
    }
    int tx = threadIdx.x & 31, ty = threadIdx.x >> 5;
#pragma unroll
    for (int i = 0; i < 4; i++) {
        int r = ty + i * 8;
        tile[r][tx] = W[(size_t)(k0 + r) * N + n0 + tx];
    }
    __syncthreads();
#pragma unroll
    for (int i = 0; i < 4; i++) {
        int r = ty + i * 8;
        Wt[(size_t)(n0 + r) * 1024 + k0 + tx] = bfbits(tile[tx][r]);
    }
}

// ---------------------------------------------------------------- QKV GEMM
// R15 = R12 verbatim (measured 44.5us): 128x128 tile, 256 threads/4 waves,
// per-wave 64x64 (acc[4][4]), glds dbuf, grid 768, 2D XCD chunk 12n x 8m.
// V^T scattered in epilogue (R9 t-permute, R11 ushort4-merged).
__global__ __launch_bounds__(256) void qkv_gemm_kernel(
    const unsigned short* __restrict__ A, const unsigned short* __restrict__ Bt,
    const float* __restrict__ bias, unsigned short* __restrict__ Qb,
    unsigned short* __restrict__ Kb, unsigned short* __restrict__ Vtb) {
    __shared__ unsigned short As[2][128 * 32];
    __shared__ unsigned short Bs[2][128 * 32];
    const int wg = blockIdx.x;                 // 0..767
    const int xcd = wg & 7, local = wg >> 3;   // local 0..95
    const int n_t = (xcd >> 2) * 12 + local % 12;   // 0..23
    const int m_t = (xcd & 3) * 8 + local / 12;     // 0..31
    const int m0 = m_t * 128, n0 = n_t * 128;
    const int tid = threadIdx.x;
    const int lane = tid & 63, w = tid >> 6;
    const int ln = lane & 15, quad = lane >> 4;
    const int wm = (w >> 1) * 64, wn = (w & 1) * 64;
    const int sr = lane >> 2, sc = (lane & 3) * 8;
    f32x4 acc[4][4] = {};
#pragma unroll
    for (int i = 0; i < 2; i++) {
        int r0 = w * 32 + i * 16;
        glds16(&A[(size_t)(m0 + r0 + sr) * 1024 + sc], &As[0][r0 * 32]);
        glds16(&Bt[(size_t)(n0 + r0 + sr) * 1024 + sc], &Bs[0][r0 * 32]);
    }
    __syncthreads();
    for (int kt = 0; kt < 32; kt++) {
        const int cur = kt & 1;
        if (kt + 1 < 32) {
            const int nxt = cur ^ 1;
            const int kc = (kt + 1) * 32;
#pragma unroll
            for (int i = 0; i < 2; i++) {
                int r0 = w * 32 + i * 16;
                glds16(&A[(size_t)(m0 + r0 + sr) * 1024 + kc + sc], &As[nxt][r0 * 32]);
                glds16(&Bt[(size_t)(n0 + r0 + sr) * 1024 + kc + sc], &Bs[nxt][r0 * 32]);
            }
        }
        bf16x8 af[4], bf[4];
#pragma unroll
        for (int mi = 0; mi < 4; mi++)
            af[mi] = ld8(&As[cur][(wm + mi * 16 + ln) * 32 + quad * 8]);
#pragma unroll
        for (int ni = 0; ni < 4; ni++)
            bf[ni] = ld8(&Bs[cur][(wn + ni * 16 + ln) * 32 + quad * 8]);
#pragma unroll
        for (int mi = 0; mi < 4; mi++)
#pragma unroll
            for (int ni = 0; ni < 4; ni++)
                acc[mi][ni] = mfma32(af[mi], bf[ni], acc[mi][ni]);
        __syncthreads();
    }
#pragma unroll
    for (int mi = 0; mi < 4; mi++)
#pragma unroll
        for (int ni = 0; ni < 4; ni++) {
            int gn = n0 + wn + ni * 16 + ln;
            float bi = bias[gn];
            int h = gn / 192, rr = gn - h * 192;
            int gm0 = m0 + wm + mi * 16 + quad * 4;
            int b = gm0 >> 11, t0 = gm0 & 2047;
            float vv[4];
#pragma unroll
            for (int r = 0; r < 4; r++) vv[r] = acc[mi][ni][r] + bi;
            if (rr < 64) {
                size_t base = ((size_t)(b * 16 + h) * 2048 + t0) * 64 + rr;
#pragma unroll
                for (int r = 0; r < 4; r++)
                    Qb[base + (size_t)r * 64] = bfbits(vv[r] * QSCALE);
            } else if (rr < 128) {
                size_t base = ((size_t)(b * 16 + h) * 2048 + t0) * 64 + rr - 64;
#pragma unroll
                for (int r = 0; r < 4; r++)
                    Kb[base + (size_t)r * 64] = bfbits(vv[r]);
            } else {
                // R9 permute: t=16b'+4q+r -> 8q+4b'+r ; bit4 of t0 = mi&1
                // (wm multiples of 64) -> thread's 4 r-values tp-contiguous.
                int tp0 = (t0 & ~31) | (quad << 3) | ((mi & 1) << 2);
                ushort4 pk;
                pk.x = bfbits(vv[0]); pk.y = bfbits(vv[1]);
                pk.z = bfbits(vv[2]); pk.w = bfbits(vv[3]);
                *(ushort4*)&Vtb[((size_t)(b * 16 + h) * 64 + (rr - 128)) * 2048
                                + tp0] = pk;
            }
        }
}

// ---------------------------------------------------------------- attention
// One 512-thread block = both split-K halves (waves 0-3 ks=0, 4-7 ks=1),
// per-half 32KB LDS loop state; in-kernel combine via XOR-swizzled LDS
// exchange. Grid 512 = (bh,qt), XCD-chunked: 4 bh-panels per XCD.
// R12: raw v_exp_f32, pinned-zero MFMA C-init, v_rcp epilogue.
// R15: s_setprio(1) around MFMA clusters (T5).
__global__ __launch_bounds__(512)
__attribute__((amdgpu_waves_per_eu(4, 4)))
void attn_kernel(
    const unsigned short* __restrict__ Q, const unsigned short* __restrict__ K,
    const unsigned short* __restrict__ Vt, unsigned short* __restrict__ Ob) {
    __shared__ unsigned short smem[2][2][2][4096];  // [ks][K/V][buf][64*64]
    const int wg  = blockIdx.x;                 // 0..511
    const int xcd = wg & 7, local = wg >> 3;    // local 0..63
    const int bh  = xcd * 4 + (local >> 4);     // 0..31 (4 bh per XCD)
    const int qt  = local & 15;
    const int tid = threadIdx.x;
    const int lane = tid & 63, w = tid >> 6;    // w 0..7
    const int w4 = w & 3, ks = w >> 2;
    const int ln = lane & 15, quad = lane >> 4;
    const int lr = lane >> 3, lg = lane & 7;
    const int e = ln & 7;

    unsigned short (*Ks)[4096] = smem[ks][0];   // [2][4096] dbuf contiguous
    unsigned short (*Vs)[4096] = smem[ks][1];

    const unsigned short* Qg = Q + ((size_t)bh * 2048 + qt * 128) * 64;
    const unsigned short* Kg = K + ((size_t)bh * 2048 + ks * 1024) * 64;
    const unsigned short* Vg = Vt + (size_t)bh * 64 * 2048 + ks * 1024;

    // Q fragments (B-operand: n=q=ln, k=d)
    bf16x8 qf[2][2];
#pragma unroll
    for (int h = 0; h < 2; h++) {
        const unsigned short* qp = Qg + (size_t)(w4 * 32 + h * 16 + ln) * 64;
        qf[h][0] = ld8(qp + quad * 8);
        qf[h][1] = ld8(qp + 32 + quad * 8);
    }

    // loop-invariant LDS compute-read bases (+ms*1024/+df*1024 and
    // +parity*4096 are constant offsets -> ds_read immediates)
    const unsigned short* kb0 = &Ks[0][ln * 64 + (quad ^ e) * 8];
    const unsigned short* kb1 = &Ks[0][ln * 64 + ((4 + quad) ^ e) * 8];
    const unsigned short* vp0 = &Vs[0][ln * 64 + (quad ^ e) * 8];
    const unsigned short* vp1 = &Vs[0][ln * 64 + ((4 + quad) ^ e) * 8];

    // loop-invariant staging offsets (lg^lr is lane-constant)
    const int kof0 = (w4 * 16 + lr) * 64 + (lg ^ lr) * 8;
    const int kof1 = (w4 * 16 + 8 + lr) * 64 + (lg ^ lr) * 8;
    const int vof0 = (w4 * 16 + lr) * 2048 + (lg ^ lr) * 8;
    const int vof1 = (w4 * 16 + 8 + lr) * 2048 + (lg ^ lr) * 8;
    unsigned short* kd0[2] = {&Ks[0][(w4 * 16) * 64], &Ks[1][(w4 * 16) * 64]};
    unsigned short* kd1[2] = {&Ks[0][(w4 * 16 + 8) * 64], &Ks[1][(w4 * 16 + 8) * 64]};
    unsigned short* vd0[2] = {&Vs[0][(w4 * 16) * 64], &Vs[1][(w4 * 16) * 64]};
    unsigned short* vd1[2] = {&Vs[0][(w4 * 16 + 8) * 64], &Vs[1][(w4 * 16 + 8) * 64]};

    // stage tile 0
    glds16(Kg + kof0, kd0[0]);
    glds16(Kg + kof1, kd1[0]);
    glds16(Vg + vof0, vd0[0]);
    glds16(Vg + vof1, vd1[0]);
    __syncthreads();

    const unsigned short* KgR = Kg + 4096;   // next K tile (64 rows x 64)
    const unsigned short* VgR = Vg + 64;     // next V tile (64 t-cols)

    bf16x8 ones8;
#pragma unroll
    for (int j = 0; j < 8; j++) ones8[j] = __bf16(1.0f);
    // R12: pinned zero C-operand (asm keep-alive prevents remat -> no
    // per-tile 32x v_mov zero-init of the s tiles).
    f32x4 zero4 = {};
    asm volatile("" : "+v"(zero4));
    f32x4 o[2][4] = {};
    f32x4 lacc[2] = {};

#define ATTN_TILE(CUR, PREF)                                                  \
    do {                                                                      \
        if (PREF) {                                                           \
            glds16(KgR + kof0, kd0[CUR ^ 1]);                                 \
            glds16(KgR + kof1, kd1[CUR ^ 1]);                                 \
            glds16(VgR + vof0, vd0[CUR ^ 1]);                                 \
            glds16(VgR + vof1, vd1[CUR ^ 1]);                                 \
            KgR += 4096; VgR += 64;                                           \
        }                                                                     \
        f32x4 s[2][4];                                                        \
        __builtin_amdgcn_s_setprio(1);                                        \
        _Pragma("unroll")                                                     \
        for (int ms = 0; ms < 4; ms++) {                                      \
            bf16x8 a0 = ld8(kb0 + (CUR) * 4096 + ms * 1024);                  \
            bf16x8 a1 = ld8(kb1 + (CUR) * 4096 + ms * 1024);                  \
            _Pragma("unroll")                                                 \
            for (int h = 0; h < 2; h++) {                                     \
                s[h][ms] = mfma32(a0, qf[h][0], zero4);                       \
                s[h][ms] = mfma32(a1, qf[h][1], s[h][ms]);                    \
            }                                                                 \
        }                                                                     \
        __builtin_amdgcn_s_setprio(0);                                        \
        bf16x8 pb8[2][2];                                                     \
        _Pragma("unroll")                                                     \
        for (int h = 0; h < 2; h++)                                           \
            _Pragma("unroll")                                                 \
            for (int p = 0; p < 2; p++) {                                     \
                f32x4 e0, e1;                                                 \
                e0[0] = EXP2(s[h][2 * p][0]); e0[1] = EXP2(s[h][2 * p][1]);   \
                e0[2] = EXP2(s[h][2 * p][2]); e0[3] = EXP2(s[h][2 * p][3]);   \
                e1[0] = EXP2(s[h][2 * p + 1][0]);                             \
                e1[1] = EXP2(s[h][2 * p + 1][1]);                             \
                e1[2] = EXP2(s[h][2 * p + 1][2]);                             \
                e1[3] = EXP2(s[h][2 * p + 1][3]);                             \
                pb8[h][p][0] = __bf16(e0[0]); pb8[h][p][1] = __bf16(e0[1]);   \
                pb8[h][p][2] = __bf16(e0[2]); pb8[h][p][3] = __bf16(e0[3]);   \
                pb8[h][p][4] = __bf16(e1[0]); pb8[h][p][5] = __bf16(e1[1]);   \
                pb8[h][p][6] = __bf16(e1[2]); pb8[h][p][7] = __bf16(e1[3]);   \
            }                                                                 \
        __builtin_amdgcn_s_setprio(1);                                        \
        _Pragma("unroll")                                                     \
        for (int h = 0; h < 2; h++)                                           \
            _Pragma("unroll")                                                 \
            for (int p = 0; p < 2; p++)                                       \
                lacc[h] = mfma32(ones8, pb8[h][p], lacc[h]);                  \
        _Pragma("unroll")                                                     \
        for (int df = 0; df < 4; df++) {                                      \
            bf16x8 a80 = ld8(vp0 + (CUR) * 4096 + df * 1024);                 \
            o[0][df] = mfma32(a80, pb8[0][0], o[0][df]);                      \
            o[1][df] = mfma32(a80, pb8[1][0], o[1][df]);                      \
            bf16x8 a81 = ld8(vp1 + (CUR) * 4096 + df * 1024);                 \
            o[0][df] = mfma32(a81, pb8[0][1], o[0][df]);                      \
            o[1][df] = mfma32(a81, pb8[1][1], o[1][df]);                      \
        }                                                                     \
        __builtin_amdgcn_s_setprio(0);                                        \
        __syncthreads();                                                      \
    } while (0)

    for (int it = 0; it < 8; it++) {
        ATTN_TILE(0, true);                 // tile 2*it, prefetch 2*it+1
        ATTN_TILE(1, (it < 7));             // tile 2*it+1, prefetch 2*it+2
    }
#undef ATTN_TILE

    // ---- in-kernel split-K combine (LDS exchange; loop LDS now dead).
    // XOR-swizzled 16B chunks: chunk = slot*8 + (j ^ (slot&7)) -> for fixed
    // j the 64 lanes' start banks cycle all 32 banks -> conflict-free.
    float* xf = (float*)&smem[0][0][0][0];
    const int slot = w4 * 64 + lane;            // 0..255
    if (ks) {
#pragma unroll
        for (int h = 0; h < 2; h++)
#pragma unroll
            for (int df = 0; df < 4; df++) {
                int j = h * 4 + df;
                *(f32x4*)(xf + (size_t)(slot * 8 + (j ^ (slot & 7))) * 4) = o[h][df];
            }
        xf[8192 + slot * 2 + 0] = lacc[0][0];
        xf[8192 + slot * 2 + 1] = lacc[1][0];
    }
    __syncthreads();
    if (!ks) {
        float inv0 = RCP(lacc[0][0] + xf[8192 + slot * 2 + 0]);
        float inv1 = RCP(lacc[1][0] + xf[8192 + slot * 2 + 1]);
        const int b = bh >> 4, hh = bh & 15;
#pragma unroll
        for (int h = 0; h < 2; h++) {
            float inv = h ? inv1 : inv0;
            int qrow = qt * 128 + w4 * 32 + h * 16 + ln;
            size_t row = ((size_t)b * 2048 + qrow) * 1024 + hh * 64;
#pragma unroll
            for (int df = 0; df < 4; df++) {
                int j = h * 4 + df;
                f32x4 oo = *(const f32x4*)(xf + (size_t)(slot * 8 + (j ^ (slot & 7))) * 4);
                ushort4 pk;
                pk.x = bfbits((o[h][df][0] + oo[0]) * inv);
                pk.y = bfbits((o[h][df][1] + oo[1]) * inv);
                pk.z = bfbits((o[h][df][2] + oo[2]) * inv);
                pk.w = bfbits((o[h][df][3] + oo[3]) * inv);
                *(ushort4*)&Ob[row + df * 16 + quad * 4] = pk;
            }
        }
    }
}

// ---------------------------------------------------------------- out GEMM
// R11: 64x128 tile (M x N), glds dbuf. Grid 512 = 2 blocks/CU. Per-wave
// 32x64. XCD-chunked: each XCD owns 8 consecutive m-tiles x all 8 n-tiles.
__global__ __launch_bounds__(256) void out_gemm_kernel(
    const unsigned short* __restrict__ A, const unsigned short* __restrict__ Bt,
    const float* __restrict__ bias, float* __restrict__ out) {
    __shared__ unsigned short As[2][64 * 32];
    __shared__ unsigned short Bs[2][128 * 32];
    const int wg = blockIdx.x;                 // 0..511
    const int xcd = wg & 7, local = wg >> 3;   // local 0..63
    const int m_t = xcd * 8 + (local & 7);     // 0..63
    const int n_t = local >> 3;                // 0..7
    const int m0 = m_t * 64, n0 = n_t * 128;
    const int tid = threadIdx.x;
    const int lane = tid & 63, w = tid >> 6;
    const int ln = lane & 15, quad = lane >> 4;
    const int wm = (w >> 1) * 32, wn = (w & 1) * 64;
    const int sr = lane >> 2, sc = (lane & 3) * 8;
    f32x4 acc[2][4] = {};
    {
        int ra = w * 16;
        glds16(&A[(size_t)(m0 + ra + sr) * 1024 + sc], &As[0][ra * 32]);
#pragma unroll
        for (int i = 0; i < 2; i++) {
            int rb = w * 32 + i * 16;
            glds16(&Bt[(size_t)(n0 + rb + sr) * 1024 + sc], &Bs[0][rb * 32]);
        }
    }
    __syncthreads();
    for (int kt = 0; kt < 32; kt++) {
        const int cur = kt & 1;
        if (kt + 1 < 32) {
            const int nxt = cur ^ 1;
            const int kc = (kt + 1) * 32;
            int ra = w * 16;
            glds16(&A[(size_t)(m0 + ra + sr) * 1024 + kc + sc], &As[nxt][ra * 32]);
#pragma unroll
            for (int i = 0; i < 2; i++) {
                int rb = w * 32 + i * 16;
                glds16(&Bt[(size_t)(n0 + rb + sr) * 1024 + kc + sc], &Bs[nxt][rb * 32]);
            }
        }
        bf16x8 af[2], bf[4];
#pragma unroll
        for (int mi = 0; mi < 2; mi++)
            af[mi] = ld8(&As[cur][(wm + mi * 16 + ln) * 32 + quad * 8]);
#pragma unroll
        for (int ni = 0; ni < 4; ni++)
            bf[ni] = ld8(&Bs[cur][(wn + ni * 16 + ln) * 32 + quad * 8]);
#pragma unroll
        for (int mi = 0; mi < 2; mi++)
#pragma unroll
            for (int ni = 0; ni < 4; ni++)
                acc[mi][ni] = mfma32(af[mi], bf[ni], acc[mi][ni]);
        __syncthreads();
    }
#pragma unroll
    for (int mi = 0; mi < 2; mi++)
#pragma unroll
        for (int ni = 0; ni < 4; ni++) {
            int gn = n0 + wn + ni * 16 + ln;
            float bi = bias[gn];
#pragma unroll
            for (int r = 0; r < 4; r++) {
                int gm = m0 + wm + mi * 16 + quad * 4 + r;
                out[(size_t)gm * 1024 + gn] = acc[mi][ni][r] + bi;
            }
        }
}

// ---------------------------------------------------------------------------
extern "C" void kernel_launch(void* const* d_in, const int* in_sizes, int n_in,
                              void* d_out, int out_size, void* d_ws, size_t ws_size,
                              hipStream_t stream) {
    const float* x     = (const float*)d_in[0];
    const float* W_qkv = (const float*)d_in[1];
    const float* b_qkv = (const float*)d_in[2];
    const float* W_out = (const float*)d_in[3];
    const float* b_out = (const float*)d_in[4];
    float* out = (float*)d_out;

    char* ws = (char*)d_ws;                            // 48 MB total footprint
    unsigned short* xb    = (unsigned short*)(ws);                      // 8 MB
    unsigned short* wqkvT = (unsigned short*)(ws + (size_t)( 8 << 20)); // 6 MB
    unsigned short* woutT = (unsigned short*)(ws + (size_t)(14 << 20)); // 2 MB
    unsigned short* Qb    = (unsigned short*)(ws + (size_t)(16 << 20)); // 8 MB
    unsigned short* Kb    = (unsigned short*)(ws + (size_t)(24 << 20)); // 8 MB
    unsigned short* Vtb   = (unsigned short*)(ws + (size_t)(32 << 20)); // 8 MB
    unsigned short* attnb = (unsigned short*)(ws + (size_t)(40 << 20)); // 8 MB

    prep_kernel<<<8192, 256, 0, stream>>>(x, xb, W_qkv, wqkvT, W_out, woutT);
    qkv_gemm_kernel<<<768, 256, 0, stream>>>(xb, wqkvT, b_qkv, Qb, Kb, Vtb);
    attn_kernel<<<512, 512, 0, stream>>>(Qb, Kb, Vtb, attnb);
    out_gemm_kernel<<<512, 256, 0, stream>>>(attnb, woutT, b_out, out);
}

// Round 12
// 173.905 us; speedup vs baseline: 1.1088x; 1.0180x over previous
//
#include <hip/hip_runtime.h>

// ---------------------------------------------------------------------------
// MultiHeadAttention: B=2, T=2048, C=1024, H=16, D=64
// prep (cast x -> bf16 ; transpose W_qkv, W_out -> bf16 [N][K], fused) ;
// QKV GEMM -> Q (prescaled 0.125*log2e), K [b,h,t,d], V^T [b,h,d,t] ;
// flash attention (fixed-base softmax), Q in regs, K/V glds dbuf
// XOR-swizzled LDS, precomputed bases, kt unrolled x2.
// R6: PV + row-sum packed into mfma_f32_16x16x32 (K=32), 36 MFMA/tile.
// R7: XCD-chunked swizzle (FETCH 73.8 -> 20.6 MB measured).
// R9: Vtb t-axis pre-permuted => PV A-operand is one ds_read_b128; bank
// conflicts 4.19M -> 0 (measured).
// R10: split-K fused into one 512-thread block, in-kernel LDS combine.
// R11: out GEMM 64x128 (2 blocks/CU); qkv V^T ushort4 stores; prep fused.
// R12: attn VALU diet: raw v_exp_f32, pinned zero4 C-init, v_rcp.
// R13/R14 REGRESSED (qkv tile-down / wave-up at fixed tile). R15 reverted.
// R16: qkv retiled 128x128 -> 256x192 (BK=32, 512 thr / 8 waves 4Mx2N,
// per-wave 64x96 acc[4][6]): grid 16x16 = 256 blocks = exactly 1/CU;
// BN=192 aligns tiles to whole heads (epilogue /192 division gone, Q/K/V
// class uniform per subtile); 24 MFMA + 10 ds_read per wave per barrier
// (vs 16+8) amortizes the 2-phase barrier drain. Same-K datum m248:
// 2-phase 256-class tile at K=1024 = 655 TF vs our 128^2's 505.
// ---------------------------------------------------------------------------

typedef float  f32x4  __attribute__((ext_vector_type(4)));
typedef __bf16 bf16x8 __attribute__((ext_vector_type(8)));

#define QSCALE 0.18033688011112042f   // 0.125 * log2(e)

#if __has_builtin(__builtin_amdgcn_exp2f)
#define EXP2(x) __builtin_amdgcn_exp2f(x)
#else
#define EXP2(x) exp2f(x)
#endif
#if __has_builtin(__builtin_amdgcn_rcpf)
#define RCP(x) __builtin_amdgcn_rcpf(x)
#else
#define RCP(x) (1.0f / (x))
#endif

static __device__ __forceinline__ f32x4 mfma32(bf16x8 a, bf16x8 b, f32x4 c) {
    return __builtin_amdgcn_mfma_f32_16x16x32_bf16(a, b, c, 0, 0, 0);
}

static __device__ __forceinline__ bf16x8 ld8(const unsigned short* p) {
    return __builtin_bit_cast(bf16x8, *(const uint4*)p);
}
static __device__ __forceinline__ unsigned short bfbits(float f) {
    __bf16 h = (__bf16)f;
    return __builtin_bit_cast(unsigned short, h);
}

static __device__ __forceinline__ void glds16(const unsigned short* g,
                                              unsigned short* lds_base) {
    __builtin_amdgcn_global_load_lds(
        (const __attribute__((address_space(1))) unsigned int*)g,
        (__attribute__((address_space(3))) unsigned int*)lds_base, 16, 0, 0);
}

// ------------------------------------------------------------ prep (fused)
// blocks [0,4096): cast x -> bf16 (float4/ushort4)
// blocks [4096,7168): transpose+cast W_qkv (96x32 tiles of 32x32)
// blocks [7168,8192): transpose+cast W_out (32x32 tiles)
__global__ __launch_bounds__(256) void prep_kernel(
    const float* __restrict__ x, unsigned short* __restrict__ xb,
    const float* __restrict__ Wqkv, unsigned short* __restrict__ wqkvT,
    const float* __restrict__ Wout, unsigned short* __restrict__ woutT) {
    __shared__ float tile[32][33];
    const int bid = blockIdx.x;
    if (bid < 4096) {
        int i = bid * 256 + threadIdx.x;
        float4 v = ((const float4*)x)[i];
        ushort4 o;
        o.x = bfbits(v.x); o.y = bfbits(v.y);
        o.z = bfbits(v.z); o.w = bfbits(v.w);
        ((ushort4*)xb)[i] = o;
        return;
    }
    const float* W; unsigned short* Wt; int N, n0, k0;
    if (bid < 7168) {
        int l = bid - 4096; W = Wqkv; Wt = wqkvT; N = 3072;
        n0 = (l % 96) * 32; k0 = (l / 96) * 32;
    } else {
        int l = bid - 7168; W = Wout; Wt = woutT; N = 1024;
        n0 = (l & 31) * 32; k0 = (l >> 5) * 32;
    }
    int tx = threadIdx.x & 31, ty = threadIdx.x >> 5;
#pragma unroll
    for (int i = 0; i < 4; i++) {
        int r = ty + i * 8;
        tile[r][tx] = W[(size_t)(k0 + r) * N + n0 + tx];
    }
    __syncthreads();
#pragma unroll
    for (int i = 0; i < 4; i++) {
        int r = ty + i * 8;
        Wt[(size_t)(n0 + r) * 1024 + k0 + tx] = bfbits(tile[tx][r]);
    }
}

// ---------------------------------------------------------------- QKV GEMM
// R16: 256x192 tile (M x N), BK=32, glds dbuf, 512 threads / 8 waves
// (4M x 2N, per-wave 64x96, acc[4][6]). Grid 256 = 1 block/CU exactly.
// BN=192 = one head block: h = n_t, no /192 division, Q/K/V class uniform
// per (wn,ni) subtile. V^T epilogue: R9 t-permute + R11 ushort4 stores.
// XCD chunk: (xcd&3)-> n quarter, (xcd>>2)-> m half: 4n x 8m per XCD.
__global__ __launch_bounds__(512) void qkv_gemm_kernel(
    const unsigned short* __restrict__ A, const unsigned short* __restrict__ Bt,
    const float* __restrict__ bias, unsigned short* __restrict__ Qb,
    unsigned short* __restrict__ Kb, unsigned short* __restrict__ Vtb) {
    __shared__ unsigned short As[2][256 * 32];   // 32 KB
    __shared__ unsigned short Bs[2][192 * 32];   // 24 KB
    const int wg = blockIdx.x;                 // 0..255
    const int xcd = wg & 7, local = wg >> 3;   // local 0..31
    const int n_t = (xcd & 3) * 4 + (local & 3);    // 0..15
    const int m_t = (xcd >> 2) * 8 + (local >> 2);  // 0..15
    const int m0 = m_t * 256, n0 = n_t * 192;
    const int tid = threadIdx.x;
    const int lane = tid & 63, w = tid >> 6;   // w 0..7
    const int ln = lane & 15, quad = lane >> 4;
    const int wm = (w >> 1) * 64;              // 0,64,128,192
    const int wn = (w & 1) * 96;               // 0,96
    const int sr = lane >> 2, sc = (lane & 3) * 8;  // 16 rows x 32 cols / wave

    f32x4 acc[4][6] = {};

    // staging: A rows 0..255 (2 loads/thread), B rows 0..191 (waves 0..3
    // carry the 128..191 chunk). Dest is wave-uniform base + lane*16B.
#define STAGE(BUF, KC)                                                        \
    do {                                                                      \
        glds16(&A[(size_t)(m0 + w * 16 + sr) * 1024 + (KC) + sc],             \
               &As[BUF][(w * 16) * 32]);                                      \
        glds16(&A[(size_t)(m0 + 128 + w * 16 + sr) * 1024 + (KC) + sc],       \
               &As[BUF][(128 + w * 16) * 32]);                                \
        glds16(&Bt[(size_t)(n0 + w * 16 + sr) * 1024 + (KC) + sc],            \
               &Bs[BUF][(w * 16) * 32]);                                      \
        if (w < 4)                                                            \
            glds16(&Bt[(size_t)(n0 + 128 + w * 16 + sr) * 1024 + (KC) + sc],  \
                   &Bs[BUF][(128 + w * 16) * 32]);                            \
    } while (0)

    STAGE(0, 0);
    __syncthreads();
    for (int kt = 0; kt < 32; kt++) {
        const int cur = kt & 1;
        if (kt + 1 < 32) STAGE(cur ^ 1, (kt + 1) * 32);
        bf16x8 af[4], bf[6];
#pragma unroll
        for (int mi = 0; mi < 4; mi++)
            af[mi] = ld8(&As[cur][(wm + mi * 16 + ln) * 32 + quad * 8]);
#pragma unroll
        for (int ni = 0; ni < 6; ni++)
            bf[ni] = ld8(&Bs[cur][(wn + ni * 16 + ln) * 32 + quad * 8]);
#pragma unroll
        for (int mi = 0; mi < 4; mi++)
#pragma unroll
            for (int ni = 0; ni < 6; ni++)
                acc[mi][ni] = mfma32(af[mi], bf[ni], acc[mi][ni]);
        __syncthreads();
    }
#undef STAGE

    const int h = n_t;                          // one head block per n-tile
#pragma unroll
    for (int mi = 0; mi < 4; mi++)
#pragma unroll
        for (int ni = 0; ni < 6; ni++) {
            int rr = wn + ni * 16 + ln;         // 0..191, class-uniform/tile
            float bi = bias[n0 + rr];
            int gm0 = m0 + wm + mi * 16 + quad * 4;
            int b = gm0 >> 11, t0 = gm0 & 2047;
            float vv[4];
#pragma unroll
            for (int r = 0; r < 4; r++) vv[r] = acc[mi][ni][r] + bi;
            if (rr < 64) {
                size_t base = ((size_t)(b * 16 + h) * 2048 + t0) * 64 + rr;
#pragma unroll
                for (int r = 0; r < 4; r++)
                    Qb[base + (size_t)r * 64] = bfbits(vv[r] * QSCALE);
            } else if (rr < 128) {
                size_t base = ((size_t)(b * 16 + h) * 2048 + t0) * 64 + rr - 64;
#pragma unroll
                for (int r = 0; r < 4; r++)
                    Kb[base + (size_t)r * 64] = bfbits(vv[r]);
            } else {
                // R9 permute: t&31 = 16*(mi&1)+4*quad+r -> 8*quad+4*(mi&1)+r
                // (wm,m0 multiples of 64) -> 4 r-values tp-contiguous.
                int tp0 = (t0 & ~31) | (quad << 3) | ((mi & 1) << 2);
                ushort4 pk;
                pk.x = bfbits(vv[0]); pk.y = bfbits(vv[1]);
                pk.z = bfbits(vv[2]); pk.w = bfbits(vv[3]);
                *(ushort4*)&Vtb[((size_t)(b * 16 + h) * 64 + (rr - 128)) * 2048
                                + tp0] = pk;
            }
        }
}

// ---------------------------------------------------------------- attention
// One 512-thread block = both split-K halves (waves 0-3 ks=0, 4-7 ks=1),
// per-half 32KB LDS loop state; in-kernel combine via XOR-swizzled LDS
// exchange. Grid 512 = (bh,qt), XCD-chunked: 4 bh-panels per XCD.
// R12: raw v_exp_f32, pinned-zero MFMA C-init, v_rcp epilogue.
// R15: s_setprio(1) around MFMA clusters (T5).
__global__ __launch_bounds__(512)
__attribute__((amdgpu_waves_per_eu(4, 4)))
void attn_kernel(
    const unsigned short* __restrict__ Q, const unsigned short* __restrict__ K,
    const unsigned short* __restrict__ Vt, unsigned short* __restrict__ Ob) {
    __shared__ unsigned short smem[2][2][2][4096];  // [ks][K/V][buf][64*64]
    const int wg  = blockIdx.x;                 // 0..511
    const int xcd = wg & 7, local = wg >> 3;    // local 0..63
    const int bh  = xcd * 4 + (local >> 4);     // 0..31 (4 bh per XCD)
    const int qt  = local & 15;
    const int tid = threadIdx.x;
    const int lane = tid & 63, w = tid >> 6;    // w 0..7
    const int w4 = w & 3, ks = w >> 2;
    const int ln = lane & 15, quad = lane >> 4;
    const int lr = lane >> 3, lg = lane & 7;
    const int e = ln & 7;

    unsigned short (*Ks)[4096] = smem[ks][0];   // [2][4096] dbuf contiguous
    unsigned short (*Vs)[4096] = smem[ks][1];

    const unsigned short* Qg = Q + ((size_t)bh * 2048 + qt * 128) * 64;
    const unsigned short* Kg = K + ((size_t)bh * 2048 + ks * 1024) * 64;
    const unsigned short* Vg = Vt + (size_t)bh * 64 * 2048 + ks * 1024;

    // Q fragments (B-operand: n=q=ln, k=d)
    bf16x8 qf[2][2];
#pragma unroll
    for (int h = 0; h < 2; h++) {
        const unsigned short* qp = Qg + (size_t)(w4 * 32 + h * 16 + ln) * 64;
        qf[h][0] = ld8(qp + quad * 8);
        qf[h][1] = ld8(qp + 32 + quad * 8);
    }

    // loop-invariant LDS compute-read bases (+ms*1024/+df*1024 and
    // +parity*4096 are constant offsets -> ds_read immediates)
    const unsigned short* kb0 = &Ks[0][ln * 64 + (quad ^ e) * 8];
    const unsigned short* kb1 = &Ks[0][ln * 64 + ((4 + quad) ^ e) * 8];
    const unsigned short* vp0 = &Vs[0][ln * 64 + (quad ^ e) * 8];
    const unsigned short* vp1 = &Vs[0][ln * 64 + ((4 + quad) ^ e) * 8];

    // loop-invariant staging offsets (lg^lr is lane-constant)
    const int kof0 = (w4 * 16 + lr) * 64 + (lg ^ lr) * 8;
    const int kof1 = (w4 * 16 + 8 + lr) * 64 + (lg ^ lr) * 8;
    const int vof0 = (w4 * 16 + lr) * 2048 + (lg ^ lr) * 8;
    const int vof1 = (w4 * 16 + 8 + lr) * 2048 + (lg ^ lr) * 8;
    unsigned short* kd0[2] = {&Ks[0][(w4 * 16) * 64], &Ks[1][(w4 * 16) * 64]};
    unsigned short* kd1[2] = {&Ks[0][(w4 * 16 + 8) * 64], &Ks[1][(w4 * 16 + 8) * 64]};
    unsigned short* vd0[2] = {&Vs[0][(w4 * 16) * 64], &Vs[1][(w4 * 16) * 64]};
    unsigned short* vd1[2] = {&Vs[0][(w4 * 16 + 8) * 64], &Vs[1][(w4 * 16 + 8) * 64]};

    // stage tile 0
    glds16(Kg + kof0, kd0[0]);
    glds16(Kg + kof1, kd1[0]);
    glds16(Vg + vof0, vd0[0]);
    glds16(Vg + vof1, vd1[0]);
    __syncthreads();

    const unsigned short* KgR = Kg + 4096;   // next K tile (64 rows x 64)
    const unsigned short* VgR = Vg + 64;     // next V tile (64 t-cols)

    bf16x8 ones8;
#pragma unroll
    for (int j = 0; j < 8; j++) ones8[j] = __bf16(1.0f);
    // R12: pinned zero C-operand (asm keep-alive prevents remat -> no
    // per-tile 32x v_mov zero-init of the s tiles).
    f32x4 zero4 = {};
    asm volatile("" : "+v"(zero4));
    f32x4 o[2][4] = {};
    f32x4 lacc[2] = {};

#define ATTN_TILE(CUR, PREF)                                                  \
    do {                                                                      \
        if (PREF) {                                                           \
            glds16(KgR + kof0, kd0[CUR ^ 1]);                                 \
            glds16(KgR + kof1, kd1[CUR ^ 1]);                                 \
            glds16(VgR + vof0, vd0[CUR ^ 1]);                                 \
            glds16(VgR + vof1, vd1[CUR ^ 1]);                                 \
            KgR += 4096; VgR += 64;                                           \
        }                                                                     \
        f32x4 s[2][4];                                                        \
        __builtin_amdgcn_s_setprio(1);                                        \
        _Pragma("unroll")                                                     \
        for (int ms = 0; ms < 4; ms++) {                                      \
            bf16x8 a0 = ld8(kb0 + (CUR) * 4096 + ms * 1024);                  \
            bf16x8 a1 = ld8(kb1 + (CUR) * 4096 + ms * 1024);                  \
            _Pragma("unroll")                                                 \
            for (int h = 0; h < 2; h++) {                                     \
                s[h][ms] = mfma32(a0, qf[h][0], zero4);                       \
                s[h][ms] = mfma32(a1, qf[h][1], s[h][ms]);                    \
            }                                                                 \
        }                                                                     \
        __builtin_amdgcn_s_setprio(0);                                        \
        bf16x8 pb8[2][2];                                                     \
        _Pragma("unroll")                                                     \
        for (int h = 0; h < 2; h++)                                           \
            _Pragma("unroll")                                                 \
            for (int p = 0; p < 2; p++) {                                     \
                f32x4 e0, e1;                                                 \
                e0[0] = EXP2(s[h][2 * p][0]); e0[1] = EXP2(s[h][2 * p][1]);   \
                e0[2] = EXP2(s[h][2 * p][2]); e0[3] = EXP2(s[h][2 * p][3]);   \
                e1[0] = EXP2(s[h][2 * p + 1][0]);                             \
                e1[1] = EXP2(s[h][2 * p + 1][1]);                             \
                e1[2] = EXP2(s[h][2 * p + 1][2]);                             \
                e1[3] = EXP2(s[h][2 * p + 1][3]);                             \
                pb8[h][p][0] = __bf16(e0[0]); pb8[h][p][1] = __bf16(e0[1]);   \
                pb8[h][p][2] = __bf16(e0[2]); pb8[h][p][3] = __bf16(e0[3]);   \
                pb8[h][p][4] = __bf16(e1[0]); pb8[h][p][5] = __bf16(e1[1]);   \
                pb8[h][p][6] = __bf16(e1[2]); pb8[h][p][7] = __bf16(e1[3]);   \
            }                                                                 \
        __builtin_amdgcn_s_setprio(1);                                        \
        _Pragma("unroll")                                                     \
        for (int h = 0; h < 2; h++)                                           \
            _Pragma("unroll")                                                 \
            for (int p = 0; p < 2; p++)                                       \
                lacc[h] = mfma32(ones8, pb8[h][p], lacc[h]);                  \
        _Pragma("unroll")                                                     \
        for (int df = 0; df < 4; df++) {                                      \
            bf16x8 a80 = ld8(vp0 + (CUR) * 4096 + df * 1024);                 \
            o[0][df] = mfma32(a80, pb8[0][0], o[0][df]);                      \
            o[1][df] = mfma32(a80, pb8[1][0], o[1][df]);                      \
            bf16x8 a81 = ld8(vp1 + (CUR) * 4096 + df * 1024);                 \
            o[0][df] = mfma32(a81, pb8[0][1], o[0][df]);                      \
            o[1][df] = mfma32(a81, pb8[1][1], o[1][df]);                      \
        }                                                                     \
        __builtin_amdgcn_s_setprio(0);                                        \
        __syncthreads();                                                      \
    } while (0)

    for (int it = 0; it < 8; it++) {
        ATTN_TILE(0, true);                 // tile 2*it, prefetch 2*it+1
        ATTN_TILE(1, (it < 7));             // tile 2*it+1, prefetch 2*it+2
    }
#undef ATTN_TILE

    // ---- in-kernel split-K combine (LDS exchange; loop LDS now dead).
    // XOR-swizzled 16B chunks: chunk = slot*8 + (j ^ (slot&7)) -> for fixed
    // j the 64 lanes' start banks cycle all 32 banks -> conflict-free.
    float* xf = (float*)&smem[0][0][0][0];
    const int slot = w4 * 64 + lane;            // 0..255
    if (ks) {
#pragma unroll
        for (int h = 0; h < 2; h++)
#pragma unroll
            for (int df = 0; df < 4; df++) {
                int j = h * 4 + df;
                *(f32x4*)(xf + (size_t)(slot * 8 + (j ^ (slot & 7))) * 4) = o[h][df];
            }
        xf[8192 + slot * 2 + 0] = lacc[0][0];
        xf[8192 + slot * 2 + 1] = lacc[1][0];
    }
    __syncthreads();
    if (!ks) {
        float inv0 = RCP(lacc[0][0] + xf[8192 + slot * 2 + 0]);
        float inv1 = RCP(lacc[1][0] + xf[8192 + slot * 2 + 1]);
        const int b = bh >> 4, hh = bh & 15;
#pragma unroll
        for (int h = 0; h < 2; h++) {
            float inv = h ? inv1 : inv0;
            int qrow = qt * 128 + w4 * 32 + h * 16 + ln;
            size_t row = ((size_t)b * 2048 + qrow) * 1024 + hh * 64;
#pragma unroll
            for (int df = 0; df < 4; df++) {
                int j = h * 4 + df;
                f32x4 oo = *(const f32x4*)(xf + (size_t)(slot * 8 + (j ^ (slot & 7))) * 4);
                ushort4 pk;
                pk.x = bfbits((o[h][df][0] + oo[0]) * inv);
                pk.y = bfbits((o[h][df][1] + oo[1]) * inv);
                pk.z = bfbits((o[h][df][2] + oo[2]) * inv);
                pk.w = bfbits((o[h][df][3] + oo[3]) * inv);
                *(ushort4*)&Ob[row + df * 16 + quad * 4] = pk;
            }
        }
    }
}

// ---------------------------------------------------------------- out GEMM
// R11: 64x128 tile (M x N), glds dbuf. Grid 512 = 2 blocks/CU. Per-wave
// 32x64. XCD-chunked: each XCD owns 8 consecutive m-tiles x all 8 n-tiles.
__global__ __launch_bounds__(256) void out_gemm_kernel(
    const unsigned short* __restrict__ A, const unsigned short* __restrict__ Bt,
    const float* __restrict__ bias, float* __restrict__ out) {
    __shared__ unsigned short As[2][64 * 32];
    __shared__ unsigned short Bs[2][128 * 32];
    const int wg = blockIdx.x;                 // 0..511
    const int xcd = wg & 7, local = wg >> 3;   // local 0..63
    const int m_t = xcd * 8 + (local & 7);     // 0..63
    const int n_t = local >> 3;                // 0..7
    const int m0 = m_t * 64, n0 = n_t * 128;
    const int tid = threadIdx.x;
    const int lane = tid & 63, w = tid >> 6;
    const int ln = lane & 15, quad = lane >> 4;
    const int wm = (w >> 1) * 32, wn = (w & 1) * 64;
    const int sr = lane >> 2, sc = (lane & 3) * 8;
    f32x4 acc[2][4] = {};
    {
        int ra = w * 16;
        glds16(&A[(size_t)(m0 + ra + sr) * 1024 + sc], &As[0][ra * 32]);
#pragma unroll
        for (int i = 0; i < 2; i++) {
            int rb = w * 32 + i * 16;
            glds16(&Bt[(size_t)(n0 + rb + sr) * 1024 + sc], &Bs[0][rb * 32]);
        }
    }
    __syncthreads();
    for (int kt = 0; kt < 32; kt++) {
        const int cur = kt & 1;
        if (kt + 1 < 32) {
            const int nxt = cur ^ 1;
            const int kc = (kt + 1) * 32;
            int ra = w * 16;
            glds16(&A[(size_t)(m0 + ra + sr) * 1024 + kc + sc], &As[nxt][ra * 32]);
#pragma unroll
            for (int i = 0; i < 2; i++) {
                int rb = w * 32 + i * 16;
                glds16(&Bt[(size_t)(n0 + rb + sr) * 1024 + kc + sc], &Bs[nxt][rb * 32]);
            }
        }
        bf16x8 af[2], bf[4];
#pragma unroll
        for (int mi = 0; mi < 2; mi++)
            af[mi] = ld8(&As[cur][(wm + mi * 16 + ln) * 32 + quad * 8]);
#pragma unroll
        for (int ni = 0; ni < 4; ni++)
            bf[ni] = ld8(&Bs[cur][(wn + ni * 16 + ln) * 32 + quad * 8]);
#pragma unroll
        for (int mi = 0; mi < 2; mi++)
#pragma unroll
            for (int ni = 0; ni < 4; ni++)
                acc[mi][ni] = mfma32(af[mi], bf[ni], acc[mi][ni]);
        __syncthreads();
    }
#pragma unroll
    for (int mi = 0; mi < 2; mi++)
#pragma unroll
        for (int ni = 0; ni < 4; ni++) {
            int gn = n0 + wn + ni * 16 + ln;
            float bi = bias[gn];
#pragma unroll
            for (int r = 0; r < 4; r++) {
                int gm = m0 + wm + mi * 16 + quad * 4 + r;
                out[(size_t)gm * 1024 + gn] = acc[mi][ni][r] + bi;
            }
        }
}

// ---------------------------------------------------------------------------
extern "C" void kernel_launch(void* const* d_in, const int* in_sizes, int n_in,
                              void* d_out, int out_size, void* d_ws, size_t ws_size,
                              hipStream_t stream) {
    const float* x     = (const float*)d_in[0];
    const float* W_qkv = (const float*)d_in[1];
    const float* b_qkv = (const float*)d_in[2];
    const float* W_out = (const float*)d_in[3];
    const float* b_out = (const float*)d_in[4];
    float* out = (float*)d_out;

    char* ws = (char*)d_ws;                            // 48 MB total footprint
    unsigned short* xb    = (unsigned short*)(ws);                      // 8 MB
    unsigned short* wqkvT = (unsigned short*)(ws + (size_t)( 8 << 20)); // 6 MB
    unsigned short* woutT = (unsigned short*)(ws + (size_t)(14 << 20)); // 2 MB
    unsigned short* Qb    = (unsigned short*)(ws + (size_t)(16 << 20)); // 8 MB
    unsigned short* Kb    = (unsigned short*)(ws + (size_t)(24 << 20)); // 8 MB
    unsigned short* Vtb   = (unsigned short*)(ws + (size_t)(32 << 20)); // 8 MB
    unsigned short* attnb = (unsigned short*)(ws + (size_t)(40 << 20)); // 8 MB

    prep_kernel<<<8192, 256, 0, stream>>>(x, xb, W_qkv, wqkvT, W_out, woutT);
    qkv_gemm_kernel<<<256, 512, 0, stream>>>(xb, wqkvT, b_qkv, Qb, Kb, Vtb);
    attn_kernel<<<512, 512, 0, stream>>>(Qb, Kb, Vtb, attnb);
    out_gemm_kernel<<<512, 256, 0, stream>>>(attnb, woutT, b_out, out);
}

// Round 13
// 171.553 us; speedup vs baseline: 1.1240x; 1.0137x over previous
//
#include <hip/hip_runtime.h>

// ---------------------------------------------------------------------------
// MultiHeadAttention: B=2, T=2048, C=1024, H=16, D=64
// prep (cast x -> bf16 ; transpose W_qkv, W_out -> bf16 [N][K], fused) ;
// QKV GEMM -> Q (prescaled 0.125*log2e), K [b,h,t,d], V^T [b,h,d,t] ;
// flash attention (fixed-base softmax), Q in regs, K/V glds dbuf
// XOR-swizzled LDS, precomputed bases, kt unrolled x2.
// R6: PV + row-sum packed into mfma_f32_16x16x32 (K=32), 36 MFMA/tile.
// R7: XCD-chunked swizzle (FETCH 73.8 -> 20.6 MB measured).
// R9: Vtb t-axis pre-permuted => PV A-operand is one ds_read_b128.
// R10: split-K fused into one 512-thread block, in-kernel LDS combine.
// R11: out GEMM 64x128 (2 blocks/CU); qkv V^T ushort4 stores; prep fused.
// R12: attn VALU diet: raw v_exp_f32, pinned zero4 C-init, v_rcp.
// R13/R14/R16 qkv geometry variants all null-or-regressed: at EVERY
// geometry both pipes are >=80% idle -> structural stall = compiler's
// vmcnt(0) drain before each __syncthreads (prefetch must land within its
// own iteration).
// R17: qkv 3-buffer counted-vmcnt pipeline (T3/T4 minimal form) on the
// proven 128^2/4-wave base: raw s_barrier (asm, no implicit drain) +
// s_waitcnt vmcnt(4) (never 0 in steady state), stage TWO iterations
// ahead (48 KB LDS, 3 blocks/CU). Hazards: RAW via in-order vmcnt(4);
// WAR: stage(kt+2) hits buf(kt-1)%3 whose readers passed this barrier,
// issue after barrier; WAW: prior write verified by prev iter's vmcnt(4);
// all ds_reads retired pre-barrier (consumed by in-iter MFMA lgkmcnt).
// sched_barrier(0) after each asm (rule #18).
// ---------------------------------------------------------------------------

typedef float  f32x4  __attribute__((ext_vector_type(4)));
typedef __bf16 bf16x8 __attribute__((ext_vector_type(8)));

#define QSCALE 0.18033688011112042f   // 0.125 * log2(e)

#if __has_builtin(__builtin_amdgcn_exp2f)
#define EXP2(x) __builtin_amdgcn_exp2f(x)
#else
#define EXP2(x) exp2f(x)
#endif
#if __has_builtin(__builtin_amdgcn_rcpf)
#define RCP(x) __builtin_amdgcn_rcpf(x)
#else
#define RCP(x) (1.0f / (x))
#endif

static __device__ __forceinline__ f32x4 mfma32(bf16x8 a, bf16x8 b, f32x4 c) {
    return __builtin_amdgcn_mfma_f32_16x16x32_bf16(a, b, c, 0, 0, 0);
}

static __device__ __forceinline__ bf16x8 ld8(const unsigned short* p) {
    return __builtin_bit_cast(bf16x8, *(const uint4*)p);
}
static __device__ __forceinline__ unsigned short bfbits(float f) {
    __bf16 h = (__bf16)f;
    return __builtin_bit_cast(unsigned short, h);
}

static __device__ __forceinline__ void glds16(const unsigned short* g,
                                              unsigned short* lds_base) {
    __builtin_amdgcn_global_load_lds(
        (const __attribute__((address_space(1))) unsigned int*)g,
        (__attribute__((address_space(3))) unsigned int*)lds_base, 16, 0, 0);
}

// ------------------------------------------------------------ prep (fused)
// blocks [0,4096): cast x -> bf16 (float4/ushort4)
// blocks [4096,7168): transpose+cast W_qkv (96x32 tiles of 32x32)
// blocks [7168,8192): transpose+cast W_out (32x32 tiles)
__global__ __launch_bounds__(256) void prep_kernel(
    const float* __restrict__ x, unsigned short* __restrict__ xb,
    const float* __restrict__ Wqkv, unsigned short* __restrict__ wqkvT,
    const float* __restrict__ Wout, unsigned short* __restrict__ woutT) {
    __shared__ float tile[32][33];
    const int bid = blockIdx.x;
    if (bid < 4096) {
        int i = bid * 256 + threadIdx.x;
        float4 v = ((const float4*)x)[i];
        ushort4 o;
        o.x = bfbits(v.x); o.y = bfbits(v.y);
        o.z = bfbits(v.z); o.w = bfbits(v.w);
        ((ushort4*)xb)[i] = o;
        return;
    }
    const float* W; unsigned short* Wt; int N, n0, k0;
    if (bid < 7168) {
        int l = bid - 4096; W = Wqkv; Wt = wqkvT; N = 3072;
        n0 = (l % 96) * 32; k0 = (l / 96) * 32;
    } else {
        int l = bid - 7168; W = Wout; Wt = woutT; N = 1024;
        n0 = (l & 31) * 32; k0 = (l >> 5) * 32;
    }
    int tx = threadIdx.x & 31, ty = threadIdx.x >> 5;
#pragma unroll
    for (int i = 0; i < 4; i++) {
        int r = ty + i * 8;
        tile[r][tx] = W[(size_t)(k0 + r) * N + n0 + tx];
    }
    __syncthreads();
#pragma unroll
    for (int i = 0; i < 4; i++) {
        int r = ty + i * 8;
        Wt[(size_t)(n0 + r) * 1024 + k0 + tx] = bfbits(tile[tx][r]);
    }
}

// ---------------------------------------------------------------- QKV GEMM
// R17: 128x128 tile, 256 thr/4 waves (per-wave 64x64, acc[4][4]), 3-buffer
// LDS (48 KB) counted-vmcnt pipeline: stage kt+2 while computing kt; raw
// s_barrier + vmcnt(4) (vmcnt(0) only on the last iteration). Grid 768 =
// 3 blocks/CU, XCD chunk 12n x 8m. V^T epilogue: R9 t-permute + ushort4.
__global__ __launch_bounds__(256) void qkv_gemm_kernel(
    const unsigned short* __restrict__ A, const unsigned short* __restrict__ Bt,
    const float* __restrict__ bias, unsigned short* __restrict__ Qb,
    unsigned short* __restrict__ Kb, unsigned short* __restrict__ Vtb) {
    __shared__ unsigned short As[3][128 * 32];
    __shared__ unsigned short Bs[3][128 * 32];
    const int wg = blockIdx.x;                 // 0..767
    const int xcd = wg & 7, local = wg >> 3;   // local 0..95
    const int n_t = (xcd >> 2) * 12 + local % 12;   // 0..23
    const int m_t = (xcd & 3) * 8 + local / 12;     // 0..31
    const int m0 = m_t * 128, n0 = n_t * 128;
    const int tid = threadIdx.x;
    const int lane = tid & 63, w = tid >> 6;
    const int ln = lane & 15, quad = lane >> 4;
    const int wm = (w >> 1) * 64, wn = (w & 1) * 64;
    const int sr = lane >> 2, sc = (lane & 3) * 8;

    // loop-invariant read/stage bases (buffer selected by +co/+so elements)
    const unsigned short* a_rd = &As[0][(wm + ln) * 32 + quad * 8];
    const unsigned short* b_rd = &Bs[0][(wn + ln) * 32 + quad * 8];
    unsigned short* a_st0 = &As[0][(w * 32) * 32];
    unsigned short* a_st1 = &As[0][(w * 32 + 16) * 32];
    unsigned short* b_st0 = &Bs[0][(w * 32) * 32];
    unsigned short* b_st1 = &Bs[0][(w * 32 + 16) * 32];
    const unsigned short* Ag0 = &A[(size_t)(m0 + w * 32 + sr) * 1024 + sc];
    const unsigned short* Ag1 = &A[(size_t)(m0 + w * 32 + 16 + sr) * 1024 + sc];
    const unsigned short* Bg0 = &Bt[(size_t)(n0 + w * 32 + sr) * 1024 + sc];
    const unsigned short* Bg1 = &Bt[(size_t)(n0 + w * 32 + 16 + sr) * 1024 + sc];

#define QSTAGE(OFF, KC)                                                       \
    do {                                                                      \
        glds16(Ag0 + (KC), a_st0 + (OFF));                                    \
        glds16(Bg0 + (KC), b_st0 + (OFF));                                    \
        glds16(Ag1 + (KC), a_st1 + (OFF));                                    \
        glds16(Bg1 + (KC), b_st1 + (OFF));                                    \
    } while (0)

#define QCOMPUTE(CO)                                                          \
    do {                                                                      \
        bf16x8 af[4], bf[4];                                                  \
        _Pragma("unroll")                                                     \
        for (int mi = 0; mi < 4; mi++)                                        \
            af[mi] = ld8(a_rd + (CO) + mi * 512);                             \
        _Pragma("unroll")                                                     \
        for (int ni = 0; ni < 4; ni++)                                        \
            bf[ni] = ld8(b_rd + (CO) + ni * 512);                             \
        __builtin_amdgcn_s_setprio(1);                                        \
        _Pragma("unroll")                                                     \
        for (int mi = 0; mi < 4; mi++)                                        \
            _Pragma("unroll")                                                 \
            for (int ni = 0; ni < 4; ni++)                                    \
                acc[mi][ni] = mfma32(af[mi], bf[ni], acc[mi][ni]);            \
        __builtin_amdgcn_s_setprio(0);                                        \
    } while (0)

    f32x4 acc[4][4] = {};
    QSTAGE(0, 0);                 // stage kt=0 -> buf 0
    QSTAGE(4096, 32);             // stage kt=1 -> buf 1   (8 loads in flight)
    int co = 0;                   // compute-buffer element offset (kt%3)*4096
    int so = 2 * 4096;            // stage-buffer offset ((kt+2)%3)*4096
    for (int kt = 0; kt < 31; kt++) {
        asm volatile("s_waitcnt vmcnt(4)" ::: "memory");   // oldest stage done
        __builtin_amdgcn_sched_barrier(0);
        asm volatile("s_barrier" ::: "memory");
        __builtin_amdgcn_sched_barrier(0);
        if (kt + 2 < 32) QSTAGE(so, (kt + 2) * 32);
        QCOMPUTE(co);
        co = (co == 2 * 4096) ? 0 : co + 4096;
        so = (so == 2 * 4096) ? 0 : so + 4096;
    }
    asm volatile("s_waitcnt vmcnt(0)" ::: "memory");       // last stage done
    __builtin_amdgcn_sched_barrier(0);
    asm volatile("s_barrier" ::: "memory");
    __builtin_amdgcn_sched_barrier(0);
    QCOMPUTE(co);
#undef QSTAGE
#undef QCOMPUTE

#pragma unroll
    for (int mi = 0; mi < 4; mi++)
#pragma unroll
        for (int ni = 0; ni < 4; ni++) {
            int gn = n0 + wn + ni * 16 + ln;
            float bi = bias[gn];
            int h = gn / 192, rr = gn - h * 192;
            int gm0 = m0 + wm + mi * 16 + quad * 4;
            int b = gm0 >> 11, t0 = gm0 & 2047;
            float vv[4];
#pragma unroll
            for (int r = 0; r < 4; r++) vv[r] = acc[mi][ni][r] + bi;
            if (rr < 64) {
                size_t base = ((size_t)(b * 16 + h) * 2048 + t0) * 64 + rr;
#pragma unroll
                for (int r = 0; r < 4; r++)
                    Qb[base + (size_t)r * 64] = bfbits(vv[r] * QSCALE);
            } else if (rr < 128) {
                size_t base = ((size_t)(b * 16 + h) * 2048 + t0) * 64 + rr - 64;
#pragma unroll
                for (int r = 0; r < 4; r++)
                    Kb[base + (size_t)r * 64] = bfbits(vv[r]);
            } else {
                // R9 permute: t&31 = 16*(mi&1)+4*quad+r -> 8*quad+4*(mi&1)+r
                // (wm multiples of 64) -> thread's 4 r-values tp-contiguous.
                int tp0 = (t0 & ~31) | (quad << 3) | ((mi & 1) << 2);
                ushort4 pk;
                pk.x = bfbits(vv[0]); pk.y = bfbits(vv[1]);
                pk.z = bfbits(vv[2]); pk.w = bfbits(vv[3]);
                *(ushort4*)&Vtb[((size_t)(b * 16 + h) * 64 + (rr - 128)) * 2048
                                + tp0] = pk;
            }
        }
}

// ---------------------------------------------------------------- attention
// One 512-thread block = both split-K halves (waves 0-3 ks=0, 4-7 ks=1),
// per-half 32KB LDS loop state; in-kernel combine via XOR-swizzled LDS
// exchange. Grid 512 = (bh,qt), XCD-chunked: 4 bh-panels per XCD.
// R12: raw v_exp_f32, pinned-zero MFMA C-init, v_rcp epilogue.
// R15: s_setprio(1) around MFMA clusters (T5).
__global__ __launch_bounds__(512)
__attribute__((amdgpu_waves_per_eu(4, 4)))
void attn_kernel(
    const unsigned short* __restrict__ Q, const unsigned short* __restrict__ K,
    const unsigned short* __restrict__ Vt, unsigned short* __restrict__ Ob) {
    __shared__ unsigned short smem[2][2][2][4096];  // [ks][K/V][buf][64*64]
    const int wg  = blockIdx.x;                 // 0..511
    const int xcd = wg & 7, local = wg >> 3;    // local 0..63
    const int bh  = xcd * 4 + (local >> 4);     // 0..31 (4 bh per XCD)
    const int qt  = local & 15;
    const int tid = threadIdx.x;
    const int lane = tid & 63, w = tid >> 6;    // w 0..7
    const int w4 = w & 3, ks = w >> 2;
    const int ln = lane & 15, quad = lane >> 4;
    const int lr = lane >> 3, lg = lane & 7;
    const int e = ln & 7;

    unsigned short (*Ks)[4096] = smem[ks][0];   // [2][4096] dbuf contiguous
    unsigned short (*Vs)[4096] = smem[ks][1];

    const unsigned short* Qg = Q + ((size_t)bh * 2048 + qt * 128) * 64;
    const unsigned short* Kg = K + ((size_t)bh * 2048 + ks * 1024) * 64;
    const unsigned short* Vg = Vt + (size_t)bh * 64 * 2048 + ks * 1024;

    // Q fragments (B-operand: n=q=ln, k=d)
    bf16x8 qf[2][2];
#pragma unroll
    for (int h = 0; h < 2; h++) {
        const unsigned short* qp = Qg + (size_t)(w4 * 32 + h * 16 + ln) * 64;
        qf[h][0] = ld8(qp + quad * 8);
        qf[h][1] = ld8(qp + 32 + quad * 8);
    }

    // loop-invariant LDS compute-read bases (+ms*1024/+df*1024 and
    // +parity*4096 are constant offsets -> ds_read immediates)
    const unsigned short* kb0 = &Ks[0][ln * 64 + (quad ^ e) * 8];
    const unsigned short* kb1 = &Ks[0][ln * 64 + ((4 + quad) ^ e) * 8];
    const unsigned short* vp0 = &Vs[0][ln * 64 + (quad ^ e) * 8];
    const unsigned short* vp1 = &Vs[0][ln * 64 + ((4 + quad) ^ e) * 8];

    // loop-invariant staging offsets (lg^lr is lane-constant)
    const int kof0 = (w4 * 16 + lr) * 64 + (lg ^ lr) * 8;
    const int kof1 = (w4 * 16 + 8 + lr) * 64 + (lg ^ lr) * 8;
    const int vof0 = (w4 * 16 + lr) * 2048 + (lg ^ lr) * 8;
    const int vof1 = (w4 * 16 + 8 + lr) * 2048 + (lg ^ lr) * 8;
    unsigned short* kd0[2] = {&Ks[0][(w4 * 16) * 64], &Ks[1][(w4 * 16) * 64]};
    unsigned short* kd1[2] = {&Ks[0][(w4 * 16 + 8) * 64], &Ks[1][(w4 * 16 + 8) * 64]};
    unsigned short* vd0[2] = {&Vs[0][(w4 * 16) * 64], &Vs[1][(w4 * 16) * 64]};
    unsigned short* vd1[2] = {&Vs[0][(w4 * 16 + 8) * 64], &Vs[1][(w4 * 16 + 8) * 64]};

    // stage tile 0
    glds16(Kg + kof0, kd0[0]);
    glds16(Kg + kof1, kd1[0]);
    glds16(Vg + vof0, vd0[0]);
    glds16(Vg + vof1, vd1[0]);
    __syncthreads();

    const unsigned short* KgR = Kg + 4096;   // next K tile (64 rows x 64)
    const unsigned short* VgR = Vg + 64;     // next V tile (64 t-cols)

    bf16x8 ones8;
#pragma unroll
    for (int j = 0; j < 8; j++) ones8[j] = __bf16(1.0f);
    // R12: pinned zero C-operand (asm keep-alive prevents remat -> no
    // per-tile 32x v_mov zero-init of the s tiles).
    f32x4 zero4 = {};
    asm volatile("" : "+v"(zero4));
    f32x4 o[2][4] = {};
    f32x4 lacc[2] = {};

#define ATTN_TILE(CUR, PREF)                                                  \
    do {                                                                      \
        if (PREF) {                                                           \
            glds16(KgR + kof0, kd0[CUR ^ 1]);                                 \
            glds16(KgR + kof1, kd1[CUR ^ 1]);                                 \
            glds16(VgR + vof0, vd0[CUR ^ 1]);                                 \
            glds16(VgR + vof1, vd1[CUR ^ 1]);                                 \
            KgR += 4096; VgR += 64;                                           \
        }                                                                     \
        f32x4 s[2][4];                                                        \
        __builtin_amdgcn_s_setprio(1);                                        \
        _Pragma("unroll")                                                     \
        for (int ms = 0; ms < 4; ms++) {                                      \
            bf16x8 a0 = ld8(kb0 + (CUR) * 4096 + ms * 1024);                  \
            bf16x8 a1 = ld8(kb1 + (CUR) * 4096 + ms * 1024);                  \
            _Pragma("unroll")                                                 \
            for (int h = 0; h < 2; h++) {                                     \
                s[h][ms] = mfma32(a0, qf[h][0], zero4);                       \
                s[h][ms] = mfma32(a1, qf[h][1], s[h][ms]);                    \
            }                                                                 \
        }                                                                     \
        __builtin_amdgcn_s_setprio(0);                                        \
        bf16x8 pb8[2][2];                                                     \
        _Pragma("unroll")                                                     \
        for (int h = 0; h < 2; h++)                                           \
            _Pragma("unroll")                                                 \
            for (int p = 0; p < 2; p++) {                                     \
                f32x4 e0, e1;                                                 \
                e0[0] = EXP2(s[h][2 * p][0]); e0[1] = EXP2(s[h][2 * p][1]);   \
                e0[2] = EXP2(s[h][2 * p][2]); e0[3] = EXP2(s[h][2 * p][3]);   \
                e1[0] = EXP2(s[h][2 * p + 1][0]);                             \
                e1[1] = EXP2(s[h][2 * p + 1][1]);                             \
                e1[2] = EXP2(s[h][2 * p + 1][2]);                             \
                e1[3] = EXP2(s[h][2 * p + 1][3]);                             \
                pb8[h][p][0] = __bf16(e0[0]); pb8[h][p][1] = __bf16(e0[1]);   \
                pb8[h][p][2] = __bf16(e0[2]); pb8[h][p][3] = __bf16(e0[3]);   \
                pb8[h][p][4] = __bf16(e1[0]); pb8[h][p][5] = __bf16(e1[1]);   \
                pb8[h][p][6] = __bf16(e1[2]); pb8[h][p][7] = __bf16(e1[3]);   \
            }                                                                 \
        __builtin_amdgcn_s_setprio(1);                                        \
        _Pragma("unroll")                                                     \
        for (int h = 0; h < 2; h++)                                           \
            _Pragma("unroll")                                                 \
            for (int p = 0; p < 2; p++)                                       \
                lacc[h] = mfma32(ones8, pb8[h][p], lacc[h]);                  \
        _Pragma("unroll")                                                     \
        for (int df = 0; df < 4; df++) {                                      \
            bf16x8 a80 = ld8(vp0 + (CUR) * 4096 + df * 1024);                 \
            o[0][df] = mfma32(a80, pb8[0][0], o[0][df]);                      \
            o[1][df] = mfma32(a80, pb8[1][0], o[1][df]);                      \
            bf16x8 a81 = ld8(vp1 + (CUR) * 4096 + df * 1024);                 \
            o[0][df] = mfma32(a81, pb8[0][1], o[0][df]);                      \
            o[1][df] = mfma32(a81, pb8[1][1], o[1][df]);                      \
        }                                                                     \
        __builtin_amdgcn_s_setprio(0);                                        \
        __syncthreads();                                                      \
    } while (0)

    for (int it = 0; it < 8; it++) {
        ATTN_TILE(0, true);                 // tile 2*it, prefetch 2*it+1
        ATTN_TILE(1, (it < 7));             // tile 2*it+1, prefetch 2*it+2
    }
#undef ATTN_TILE

    // ---- in-kernel split-K combine (LDS exchange; loop LDS now dead).
    // XOR-swizzled 16B chunks: chunk = slot*8 + (j ^ (slot&7)) -> for fixed
    // j the 64 lanes' start banks cycle all 32 banks -> conflict-free.
    float* xf = (float*)&smem[0][0][0][0];
    const int slot = w4 * 64 + lane;            // 0..255
    if (ks) {
#pragma unroll
        for (int h = 0; h < 2; h++)
#pragma unroll
            for (int df = 0; df < 4; df++) {
                int j = h * 4 + df;
                *(f32x4*)(xf + (size_t)(slot * 8 + (j ^ (slot & 7))) * 4) = o[h][df];
            }
        xf[8192 + slot * 2 + 0] = lacc[0][0];
        xf[8192 + slot * 2 + 1] = lacc[1][0];
    }
    __syncthreads();
    if (!ks) {
        float inv0 = RCP(lacc[0][0] + xf[8192 + slot * 2 + 0]);
        float inv1 = RCP(lacc[1][0] + xf[8192 + slot * 2 + 1]);
        const int b = bh >> 4, hh = bh & 15;
#pragma unroll
        for (int h = 0; h < 2; h++) {
            float inv = h ? inv1 : inv0;
            int qrow = qt * 128 + w4 * 32 + h * 16 + ln;
            size_t row = ((size_t)b * 2048 + qrow) * 1024 + hh * 64;
#pragma unroll
            for (int df = 0; df < 4; df++) {
                int j = h * 4 + df;
                f32x4 oo = *(const f32x4*)(xf + (size_t)(slot * 8 + (j ^ (slot & 7))) * 4);
                ushort4 pk;
                pk.x = bfbits((o[h][df][0] + oo[0]) * inv);
                pk.y = bfbits((o[h][df][1] + oo[1]) * inv);
                pk.z = bfbits((o[h][df][2] + oo[2]) * inv);
                pk.w = bfbits((o[h][df][3] + oo[3]) * inv);
                *(ushort4*)&Ob[row + df * 16 + quad * 4] = pk;
            }
        }
    }
}

// ---------------------------------------------------------------- out GEMM
// R11: 64x128 tile (M x N), glds dbuf. Grid 512 = 2 blocks/CU. Per-wave
// 32x64. XCD-chunked: each XCD owns 8 consecutive m-tiles x all 8 n-tiles.
__global__ __launch_bounds__(256) void out_gemm_kernel(
    const unsigned short* __restrict__ A, const unsigned short* __restrict__ Bt,
    const float* __restrict__ bias, float* __restrict__ out) {
    __shared__ unsigned short As[2][64 * 32];
    __shared__ unsigned short Bs[2][128 * 32];
    const int wg = blockIdx.x;                 // 0..511
    const int xcd = wg & 7, local = wg >> 3;   // local 0..63
    const int m_t = xcd * 8 + (local & 7);     // 0..63
    const int n_t = local >> 3;                // 0..7
    const int m0 = m_t * 64, n0 = n_t * 128;
    const int tid = threadIdx.x;
    const int lane = tid & 63, w = tid >> 6;
    const int ln = lane & 15, quad = lane >> 4;
    const int wm = (w >> 1) * 32, wn = (w & 1) * 64;
    const int sr = lane >> 2, sc = (lane & 3) * 8;
    f32x4 acc[2][4] = {};
    {
        int ra = w * 16;
        glds16(&A[(size_t)(m0 + ra + sr) * 1024 + sc], &As[0][ra * 32]);
#pragma unroll
        for (int i = 0; i < 2; i++) {
            int rb = w * 32 + i * 16;
            glds16(&Bt[(size_t)(n0 + rb + sr) * 1024 + sc], &Bs[0][rb * 32]);
        }
    }
    __syncthreads();
    for (int kt = 0; kt < 32; kt++) {
        const int cur = kt & 1;
        if (kt + 1 < 32) {
            const int nxt = cur ^ 1;
            const int kc = (kt + 1) * 32;
            int ra = w * 16;
            glds16(&A[(size_t)(m0 + ra + sr) * 1024 + kc + sc], &As[nxt][ra * 32]);
#pragma unroll
            for (int i = 0; i < 2; i++) {
                int rb = w * 32 + i * 16;
                glds16(&Bt[(size_t)(n0 + rb + sr) * 1024 + kc + sc], &Bs[nxt][rb * 32]);
            }
        }
        bf16x8 af[2], bf[4];
#pragma unroll
        for (int mi = 0; mi < 2; mi++)
            af[mi] = ld8(&As[cur][(wm + mi * 16 + ln) * 32 + quad * 8]);
#pragma unroll
        for (int ni = 0; ni < 4; ni++)
            bf[ni] = ld8(&Bs[cur][(wn + ni * 16 + ln) * 32 + quad * 8]);
#pragma unroll
        for (int mi = 0; mi < 2; mi++)
#pragma unroll
            for (int ni = 0; ni < 4; ni++)
                acc[mi][ni] = mfma32(af[mi], bf[ni], acc[mi][ni]);
        __syncthreads();
    }
#pragma unroll
    for (int mi = 0; mi < 2; mi++)
#pragma unroll
        for (int ni = 0; ni < 4; ni++) {
            int gn = n0 + wn + ni * 16 + ln;
            float bi = bias[gn];
#pragma unroll
            for (int r = 0; r < 4; r++) {
                int gm = m0 + wm + mi * 16 + quad * 4 + r;
                out[(size_t)gm * 1024 + gn] = acc[mi][ni][r] + bi;
            }
        }
}

// ---------------------------------------------------------------------------
extern "C" void kernel_launch(void* const* d_in, const int* in_sizes, int n_in,
                              void* d_out, int out_size, void* d_ws, size_t ws_size,
                              hipStream_t stream) {
    const float* x     = (const float*)d_in[0];
    const float* W_qkv = (const float*)d_in[1];
    const float* b_qkv = (const float*)d_in[2];
    const float* W_out = (const float*)d_in[3];
    const float* b_out = (const float*)d_in[4];
    float* out = (float*)d_out;

    char* ws = (char*)d_ws;                            // 48 MB total footprint
    unsigned short* xb    = (unsigned short*)(ws);                      // 8 MB
    unsigned short* wqkvT = (unsigned short*)(ws + (size_t)( 8 << 20)); // 6 MB
    unsigned short* woutT = (unsigned short*)(ws + (size_t)(14 << 20)); // 2 MB
    unsigned short* Qb    = (unsigned short*)(ws + (size_t)(16 << 20)); // 8 MB
    unsigned short* Kb    = (unsigned short*)(ws + (size_t)(24 << 20)); // 8 MB
    unsigned short* Vtb   = (unsigned short*)(ws + (size_t)(32 << 20)); // 8 MB
    unsigned short* attnb = (unsigned short*)(ws + (size_t)(40 << 20)); // 8 MB

    prep_kernel<<<8192, 256, 0, stream>>>(x, xb, W_qkv, wqkvT, W_out, woutT);
    qkv_gemm_kernel<<<768, 256, 0, stream>>>(xb, wqkvT, b_qkv, Qb, Kb, Vtb);
    attn_kernel<<<512, 512, 0, stream>>>(Qb, Kb, Vtb, attnb);
    out_gemm_kernel<<<512, 256, 0, stream>>>(attnb, woutT, b_out, out);
}